// Round 10
// baseline (186.344 us; speedup 1.0000x reference)
//
#include <hip/hip_runtime.h>

#define PBIN 14
#define SSAMP 2
#define SCALE_F 0.0625f
#define TRANS_STD 0.1f
#define CCH 256
#define FCDIM 1024
#define NROIS 192
#define HH 128
#define WW 128
#define PP (PBIN*PBIN)      // 196
#define KDIM (CCH*PP)       // 50176

typedef __bf16 bf16x8 __attribute__((ext_vector_type(8)));
typedef float  f32x4  __attribute__((ext_vector_type(4)));
typedef unsigned u32x4 __attribute__((ext_vector_type(4)));
typedef unsigned u32x2 __attribute__((ext_vector_type(2)));

__device__ __forceinline__ unsigned short f2bf(float f) {
  unsigned u = __builtin_bit_cast(unsigned, f);
  u += 0x7FFFu + ((u >> 16) & 1u);   // RNE
  return (unsigned short)(u >> 16);
}
__device__ __forceinline__ unsigned pk2(float lo, float hi) {
  unsigned ulo = __builtin_bit_cast(unsigned, lo) + 0x8000u;
  unsigned uhi = __builtin_bit_cast(unsigned, hi) + 0x8000u;
  return __builtin_amdgcn_perm(uhi, ulo, 0x07060302u);
}
__device__ __forceinline__ float bf_lo(unsigned u) {
  return __builtin_bit_cast(float, u << 16);
}
__device__ __forceinline__ float bf_hi(unsigned u) {
  return __builtin_bit_cast(float, u & 0xFFFF0000u);
}
__device__ __forceinline__ float bf_u16(unsigned short v) {
  return __builtin_bit_cast(float, (unsigned)v << 16);
}

// -------- transpose+convert x [B,C,H,W] f32 -> xt [B,H,W,C/2] u32(bf16 pair) --
__global__ __launch_bounds__(256) void transpose_x_kernel(
    const float* __restrict__ x, unsigned* __restrict__ xt)
{
  __shared__ float tile[32][33];
  int tx = threadIdx.x, ty = threadIdx.y;     // (32, 8)
  int hw0 = blockIdx.x * 32;
  int c0  = blockIdx.y * 32;
  int b   = blockIdx.z;
  const float* xb = x + (size_t)b * CCH * HH * WW;
  unsigned* xtb   = xt + (size_t)b * (HH*WW) * (CCH/2);
#pragma unroll
  for (int k = 0; k < 4; ++k)
    tile[ty + k*8][tx] = xb[(size_t)(c0 + ty + k*8) * (HH*WW) + hw0 + tx];
  __syncthreads();
  int l  = ty*32 + tx;
  int cp = l & 15;
  int hr = l >> 4;
#pragma unroll
  for (int k = 0; k < 2; ++k) {
    int row = hr + k*16;
    unsigned pkd = pk2(tile[2*cp][row], tile[2*cp+1][row]);
    xtb[(size_t)(hw0 + row) * (CCH/2) + (c0>>1) + cp] = pkd;
  }
}

// ---------------- PSRoI pool: wave = bin, lane = channel-quad -----------------
// MODE 0: base -> bf16 [n][p*256+c]. MODE 1: read om (f32), *sigmoid(mask) -> f32.
// NOTE: sits exactly at the 64-VGPR occupancy cliff — do not add registers.
template<int MODE>
__global__ __launch_bounds__(256) void pool_kernel(
    const unsigned* __restrict__ xt, const float* __restrict__ rois,
    const float* __restrict__ om, void* __restrict__ outp)
{
  __shared__ float lds[4][256];
  const int t = threadIdx.x;
  const int wv = t >> 6, lane = t & 63;
  const int n  = blockIdx.x;
  const int p0 = blockIdx.y * 4;
  const int p  = p0 + wv;
  const int ph = p / PBIN, pw = p % PBIN;

  float rb = rois[n*5 + 0];
  float x1 = rois[n*5 + 1], y1 = rois[n*5 + 2];
  float x2 = rois[n*5 + 3], y2 = rois[n*5 + 4];
  int b = (int)rb;
  float sw = rintf(x1) * SCALE_F - 0.5f;
  float sh = rintf(y1) * SCALE_F - 0.5f;
  float ew = (rintf(x2) + 1.0f) * SCALE_F - 0.5f;
  float eh = (rintf(y2) + 1.0f) * SCALE_F - 0.5f;
  float rw = fmaxf(ew - sw, 0.1f);
  float rh = fmaxf(eh - sh, 0.1f);
  float bw = rw / PBIN, bh = rh / PBIN;
  float subw = bw / SSAMP, subh = bh / SSAMP;

  float tx = 0.f, ty = 0.f, mval = 1.f;
  if (MODE == 1) {
    const float* omr = om + (size_t)n * (3*PP);
    tx = omr[p] * TRANS_STD;
    ty = omr[PP + p] * TRANS_STD;
    mval = 1.0f / (1.0f + expf(-omr[2*PP + p]));
  }
  float wstart = pw * bw + sw + tx * rw;
  float hstart = ph * bh + sh + ty * rh;

  int offs[16];
  float wts[16];
  float cnt = 0.f;
  int base_b = b * (HH*WW);
#pragma unroll
  for (int ih = 0; ih < SSAMP; ++ih) {
#pragma unroll
    for (int iw = 0; iw < SSAMP; ++iw) {
      float wv_ = wstart + iw * subw;
      float hv_ = hstart + ih * subh;
      float validf = (wv_ >= -0.5f && wv_ <= WW - 0.5f &&
                      hv_ >= -0.5f && hv_ <= HH - 0.5f) ? 1.f : 0.f;
      cnt += validf;
      float wc = fminf(fmaxf(wv_, 0.f), WW - 1.0f);
      float hc = fminf(fmaxf(hv_, 0.f), HH - 1.0f);
      int x0 = (int)floorf(wc), y0 = (int)floorf(hc);
      int x1i = min(x0 + 1, WW - 1), y1i = min(y0 + 1, HH - 1);
      float lx = wc - (float)x0, ly = hc - (float)y0;
      int s4 = (ih*2 + iw) * 4;
      offs[s4+0] = (base_b + y0 *WW + x0 ) * (CCH/2);
      offs[s4+1] = (base_b + y0 *WW + x1i) * (CCH/2);
      offs[s4+2] = (base_b + y1i*WW + x0 ) * (CCH/2);
      offs[s4+3] = (base_b + y1i*WW + x1i) * (CCH/2);
      wts[s4+0] = validf * (1.f-ly)*(1.f-lx);
      wts[s4+1] = validf * (1.f-ly)*lx;
      wts[s4+2] = validf * ly*(1.f-lx);
      wts[s4+3] = validf * ly*lx;
    }
  }
  float inv = 1.0f / fmaxf(cnt, 1.0f);
  if (MODE == 1) inv *= mval;

  const int cl = lane * 4;
  f32x4 acc = {0.f, 0.f, 0.f, 0.f};
#pragma unroll
  for (int s = 0; s < 16; ++s) {
    u32x2 v = *(const u32x2*)&xt[offs[s] + lane*2];
    acc[0] += wts[s] * bf_lo(v[0]);
    acc[1] += wts[s] * bf_hi(v[0]);
    acc[2] += wts[s] * bf_lo(v[1]);
    acc[3] += wts[s] * bf_hi(v[1]);
  }
  acc *= inv;

  if (MODE == 0) {
    unsigned short* bout = (unsigned short*)outp;
    u32x2 pkd = { pk2(acc[0], acc[1]), pk2(acc[2], acc[3]) };
    *(u32x2*)&bout[(size_t)n*KDIM + p*CCH + cl] = pkd;
  } else {
    *(f32x4*)&lds[wv][cl] = acc;
    __syncthreads();
    float* fout = (float*)outp;
    int c = t;
    f32x4 o = { lds[0][c], lds[1][c], lds[2][c], lds[3][c] };
    *(f32x4*)&fout[(size_t)n*KDIM + (size_t)c*PP + p0] = o;
  }
}

// ---------------- split-K GEMM: partial[s] (bf16) = A(bf16 192xK) * bf16(B) ---
// BM=192, BN=128, BK=32, 8 waves as 4m x 2n (wave tile 48x64). 1D grid NB*S.
// 2-deep register prefetch (named bufs, x2-unrolled loop: all indices static).
// SWZ=1 (NB==8, S%8==0): same-split n-blocks share one XCD's L2 for A.
template<int PERM, int SWZ>
__global__ __launch_bounds__(512, 4) void gemm_splitk(
    const unsigned* __restrict__ A, int ldAu,
    const float* __restrict__ Bm, int N, int ldB,
    unsigned short* __restrict__ partial, int NB, int S, int chunks)
{
  __shared__ __align__(16) unsigned lds_a[192*20];   // [m][16 u32 + pad4]
  __shared__ __align__(16) unsigned lds_b[128*18];   // [n][16 u32(k-pairs) + pad2]

  int t   = threadIdx.x;
  int bid = blockIdx.x;
  int s, nblk;
  if (SWZ) {            // NB==8, S%8==0, grid%64==0
    int xcd = bid & 7;
    nblk    = (bid >> 3) & 7;
    s       = xcd * (S >> 3) + (bid >> 6);
  } else {
    nblk = bid % NB;
    s    = bid / NB;
  }
  int n0 = nblk * 128;
  int q = chunks / S, r = chunks % S;
  int myc = q + (s < r ? 1 : 0);
  int c0 = s*q + (s < r ? s : r);
  int k0 = c0 * 32;

  int wv = t >> 6, lane = t & 63;
  int wm = wv & 3, wn = wv >> 2;               // 4m x 2n
  int m0w = wm * 48;
  int n0w = wn * 64;
  int lrow = lane & 15, lg = lane >> 4;

  f32x4 acc[3][4];
#pragma unroll
  for (int i = 0; i < 3; ++i)
#pragma unroll
    for (int j = 0; j < 4; ++j) acc[i][j] = {0.f,0.f,0.f,0.f};

  u32x2 arA[3], arB[3];
  float bvA[8], bvB[8];
  const int am  = t >> 3;         // 0..63 (A row within 64-row pass)
  const int akp = (t & 7) * 2;    // u32-pair within 16-u32 row chunk
  const int bn  = t & 127;        // B: n within tile
  const int bk8 = (t >> 7) * 8;   // B: k-base (0,8,16,24)

  auto load_tile = [&](int it, u32x2 (&ar)[3], float (&bv)[8]) {
    int kg = k0 + it*32;
#pragma unroll
    for (int i = 0; i < 3; ++i) {
      int m = am + i*64;
      ar[i] = *(const u32x2*)&A[(size_t)m*ldAu + (kg>>1) + akp];
    }
    int gn = n0 + bn;
    bool okn = (gn < N);
#pragma unroll
    for (int i = 0; i < 8; ++i) {
      int rr = kg + bk8 + i;
      size_t srow = PERM ? ((size_t)(rr & 255)*PP + (rr >> 8)) : (size_t)rr;
      bv[i] = okn ? Bm[srow*ldB + gn] : 0.f;
    }
  };
  auto stage = [&](u32x2 (&ar)[3], float (&bv)[8]) {
#pragma unroll
    for (int i = 0; i < 3; ++i) {
      int m = am + i*64;
      *(u32x2*)&lds_a[m*20 + akp] = ar[i];
    }
    u32x2 w01 = { pk2(bv[0], bv[1]), pk2(bv[2], bv[3]) };
    u32x2 w23 = { pk2(bv[4], bv[5]), pk2(bv[6], bv[7]) };
    *(u32x2*)&lds_b[bn*18 + (bk8>>1)]     = w01;
    *(u32x2*)&lds_b[bn*18 + (bk8>>1) + 2] = w23;
  };
  auto compute = [&]() {
    bf16x8 af[3];
#pragma unroll
    for (int mf = 0; mf < 3; ++mf) {
      u32x4 ra = *(const u32x4*)&lds_a[(m0w + mf*16 + lrow)*20 + lg*4];
      af[mf] = __builtin_bit_cast(bf16x8, ra);
    }
    bf16x8 bfrag[4];
#pragma unroll
    for (int nf = 0; nf < 4; ++nf) {
      int col = n0w + nf*16 + lrow;
      u32x2 r0 = *(const u32x2*)&lds_b[col*18 + lg*4];
      u32x2 r1 = *(const u32x2*)&lds_b[col*18 + lg*4 + 2];
      u32x4 ub = { r0[0], r0[1], r1[0], r1[1] };
      bfrag[nf] = __builtin_bit_cast(bf16x8, ub);
    }
#pragma unroll
    for (int nf = 0; nf < 4; ++nf)
#pragma unroll
      for (int mf = 0; mf < 3; ++mf)
        acc[mf][nf] = __builtin_amdgcn_mfma_f32_16x16x32_bf16(af[mf], bfrag[nf], acc[mf][nf], 0, 0, 0);
  };

  load_tile(0, arA, bvA);
  if (myc > 1) load_tile(1, arB, bvB);
  for (int it = 0; it < myc; it += 2) {
    __syncthreads();
    stage(arA, bvA);
    __syncthreads();
    if (it + 2 < myc) load_tile(it + 2, arA, bvA);
    compute();
    if (it + 1 >= myc) break;
    __syncthreads();
    stage(arB, bvB);
    __syncthreads();
    if (it + 3 < myc) load_tile(it + 3, arB, bvB);
    compute();
  }

#pragma unroll
  for (int mf = 0; mf < 3; ++mf) {
#pragma unroll
    for (int nf = 0; nf < 4; ++nf) {
      int gcol = n0 + n0w + nf*16 + lrow;
      if (gcol < N) {
#pragma unroll
        for (int rr = 0; rr < 4; ++rr) {
          int m = m0w + mf*16 + lg*4 + rr;
          partial[((size_t)s*NROIS + m)*N + gcol] = f2bf(acc[mf][nf][rr]);
        }
      }
    }
  }
}

// ------- reduce bf16 partials + bias + relu -> bf16 f (4 vals/thread) ---------
__global__ __launch_bounds__(256) void reduce_kernel(
    const unsigned short* __restrict__ partial, const float* __restrict__ bias,
    unsigned short* __restrict__ outp, int N, int S)
{
  int nn = (blockIdx.x*256 + threadIdx.x) * 4;
  int m  = blockIdx.y;
  if (nn >= N) return;
  f32x4 a = *(const f32x4*)&bias[nn];
  size_t stride = (size_t)NROIS * N;
  const unsigned short* p = &partial[(size_t)m*N + nn];
#pragma unroll 4
  for (int s = 0; s < S; ++s) {
    u32x2 v = *(const u32x2*)&p[(size_t)s*stride];
    a[0] += bf_lo(v[0]); a[1] += bf_hi(v[0]);
    a[2] += bf_lo(v[1]); a[3] += bf_hi(v[1]);
  }
  a[0] = fmaxf(a[0], 0.f); a[1] = fmaxf(a[1], 0.f);
  a[2] = fmaxf(a[2], 0.f); a[3] = fmaxf(a[3], 0.f);
  u32x2 pkd = { pk2(a[0], a[1]), pk2(a[2], a[3]) };
  *(u32x2*)&outp[(size_t)m*N + nn] = pkd;
}

// ------- reduce3: om[n][d] = b3[d] + sum_s p3[s][n][d]  (f32 out, 588 wide) ---
__global__ __launch_bounds__(640) void reduce3_kernel(
    const unsigned short* __restrict__ p3, const float* __restrict__ b3,
    float* __restrict__ om, int S)
{
  int d = threadIdx.x;
  int nn = blockIdx.x;
  if (d >= 3*PP) return;
  float a = b3[d];
#pragma unroll 4
  for (int s = 0; s < S; ++s)
    a += bf_u16(p3[((size_t)s*NROIS + nn)*(3*PP) + d]);
  om[(size_t)nn*(3*PP) + d] = a;
}

extern "C" void kernel_launch(void* const* d_in, const int* in_sizes, int n_in,
                              void* d_out, int out_size, void* d_ws, size_t ws_size,
                              hipStream_t stream)
{
  const float* x    = (const float*)d_in[0];
  const float* rois = (const float*)d_in[1];
  const float* w1   = (const float*)d_in[2];
  const float* b1   = (const float*)d_in[3];
  const float* w2   = (const float*)d_in[4];
  const float* b2   = (const float*)d_in[5];
  const float* w3   = (const float*)d_in[6];
  const float* b3   = (const float*)d_in[7];

  char* ws = (char*)d_ws;
  size_t off = 0;
  unsigned* xt = (unsigned*)(ws + off);               off += (size_t)2*(HH*WW)*(CCH/2)*4;
  unsigned short* base = (unsigned short*)(ws + off); off += (size_t)NROIS*KDIM*2;
  unsigned short* f1 = (unsigned short*)(ws + off);   off += (size_t)NROIS*FCDIM*2;
  unsigned short* f2 = (unsigned short*)(ws + off);   off += (size_t)NROIS*FCDIM*2;
  float* om = (float*)(ws + off);                     off += (size_t)NROIS*(3*PP)*4;
  const int S1 = 64, S2 = 32, S3 = 16;
  unsigned short* partial1 = (unsigned short*)(ws + off); off += (size_t)S1*NROIS*FCDIM*2;  // 25.2MB
  unsigned short* partial2 = (unsigned short*)(ws + off); off += (size_t)S2*NROIS*FCDIM*2;  // 12.6MB
  unsigned short* partial3 = (unsigned short*)(ws + off); off += (size_t)S3*NROIS*(3*PP)*2; // 3.6MB
  (void)ws_size;

  // 1) transpose+bf16 x -> xt
  transpose_x_kernel<<<dim3(512, 8, 2), dim3(32, 8), 0, stream>>>(x, xt);
  // 2) base pool -> bf16 [192, 50176] (k = p*256+c)
  pool_kernel<0><<<dim3(NROIS, PP/4), 256, 0, stream>>>(xt, rois, nullptr, base);
  // 3) f1 = relu(base @ w1 + b1); 1568 K-chunks, 64 splits, XCD-swizzled
  gemm_splitk<1,1><<<8*S1, 512, 0, stream>>>((const unsigned*)base, KDIM/2, w1, FCDIM, FCDIM, partial1, 8, S1, KDIM/32);
  reduce_kernel<<<dim3(1, NROIS), 256, 0, stream>>>(partial1, b1, f1, FCDIM, S1);
  // 4) f2 = relu(f1 @ w2 + b2)
  gemm_splitk<0,1><<<8*S2, 512, 0, stream>>>((const unsigned*)f1, FCDIM/2, w2, FCDIM, FCDIM, partial2, 8, S2, FCDIM/32);
  reduce_kernel<<<dim3(1, NROIS), 256, 0, stream>>>(partial2, b2, f2, FCDIM, S2);
  // 5) partial3 = split-K of f2 @ w3 (N = 588)
  gemm_splitk<0,0><<<5*S3, 512, 0, stream>>>((const unsigned*)f2, FCDIM/2, w3, 3*PP, 3*PP, partial3, 5, S3, FCDIM/32);
  // 5b) om = b3 + sum partial3 (f32)
  reduce3_kernel<<<NROIS, 640, 0, stream>>>(partial3, b3, om, S3);
  // 6) final pool reads om, * sigmoid(mask) -> d_out
  pool_kernel<1><<<dim3(NROIS, PP/4), 256, 0, stream>>>(xt, rois, om, d_out);
}

// Round 11
// 162.245 us; speedup vs baseline: 1.1485x; 1.1485x over previous
//
#include <hip/hip_runtime.h>

#define PBIN 14
#define SSAMP 2
#define SCALE_F 0.0625f
#define TRANS_STD 0.1f
#define CCH 256
#define FCDIM 1024
#define NROIS 192
#define HH 128
#define WW 128
#define PP (PBIN*PBIN)      // 196
#define KDIM (CCH*PP)       // 50176

typedef __bf16 bf16x8 __attribute__((ext_vector_type(8)));
typedef float  f32x4  __attribute__((ext_vector_type(4)));
typedef unsigned u32x4 __attribute__((ext_vector_type(4)));
typedef unsigned u32x2 __attribute__((ext_vector_type(2)));

__device__ __forceinline__ unsigned short f2bf(float f) {
  unsigned u = __builtin_bit_cast(unsigned, f);
  u += 0x7FFFu + ((u >> 16) & 1u);   // RNE
  return (unsigned short)(u >> 16);
}
__device__ __forceinline__ unsigned pk2(float lo, float hi) {
  unsigned ulo = __builtin_bit_cast(unsigned, lo) + 0x8000u;
  unsigned uhi = __builtin_bit_cast(unsigned, hi) + 0x8000u;
  return __builtin_amdgcn_perm(uhi, ulo, 0x07060302u);
}
__device__ __forceinline__ float bf_lo(unsigned u) {
  return __builtin_bit_cast(float, u << 16);
}
__device__ __forceinline__ float bf_hi(unsigned u) {
  return __builtin_bit_cast(float, u & 0xFFFF0000u);
}
__device__ __forceinline__ float bf_u16(unsigned short v) {
  return __builtin_bit_cast(float, (unsigned)v << 16);
}

// Barrier WITHOUT the vmcnt(0) drain __syncthreads() emits: LDS writes are
// made visible via lgkmcnt(0); in-flight global prefetch loads (to VGPRs,
// no cross-wave hazard) survive the barrier so HBM stays busy. (8-phase
// template technique, learn_hip m194-m201.)
__device__ __forceinline__ void wg_barrier() {
  asm volatile("s_waitcnt lgkmcnt(0)" ::: "memory");
  __builtin_amdgcn_s_barrier();
  asm volatile("" ::: "memory");
}

// -------- transpose+convert x [B,C,H,W] f32 -> xt [B,H,W,C/2] u32(bf16 pair) --
__global__ __launch_bounds__(256) void transpose_x_kernel(
    const float* __restrict__ x, unsigned* __restrict__ xt)
{
  __shared__ float tile[32][33];
  int tx = threadIdx.x, ty = threadIdx.y;     // (32, 8)
  int hw0 = blockIdx.x * 32;
  int c0  = blockIdx.y * 32;
  int b   = blockIdx.z;
  const float* xb = x + (size_t)b * CCH * HH * WW;
  unsigned* xtb   = xt + (size_t)b * (HH*WW) * (CCH/2);
#pragma unroll
  for (int k = 0; k < 4; ++k)
    tile[ty + k*8][tx] = xb[(size_t)(c0 + ty + k*8) * (HH*WW) + hw0 + tx];
  __syncthreads();
  int l  = ty*32 + tx;
  int cp = l & 15;
  int hr = l >> 4;
#pragma unroll
  for (int k = 0; k < 2; ++k) {
    int row = hr + k*16;
    unsigned pkd = pk2(tile[2*cp][row], tile[2*cp+1][row]);
    xtb[(size_t)(hw0 + row) * (CCH/2) + (c0>>1) + cp] = pkd;
  }
}

// ---------------- PSRoI pool: wave = bin, lane = channel-quad -----------------
// MODE 0: base -> bf16 [n][p*256+c]. MODE 1: read om (f32), *sigmoid(mask) -> f32.
// NOTE: sits exactly at the 64-VGPR occupancy cliff — do not add registers.
template<int MODE>
__global__ __launch_bounds__(256) void pool_kernel(
    const unsigned* __restrict__ xt, const float* __restrict__ rois,
    const float* __restrict__ om, void* __restrict__ outp)
{
  __shared__ float lds[4][256];
  const int t = threadIdx.x;
  const int wv = t >> 6, lane = t & 63;
  const int n  = blockIdx.x;
  const int p0 = blockIdx.y * 4;
  const int p  = p0 + wv;
  const int ph = p / PBIN, pw = p % PBIN;

  float rb = rois[n*5 + 0];
  float x1 = rois[n*5 + 1], y1 = rois[n*5 + 2];
  float x2 = rois[n*5 + 3], y2 = rois[n*5 + 4];
  int b = (int)rb;
  float sw = rintf(x1) * SCALE_F - 0.5f;
  float sh = rintf(y1) * SCALE_F - 0.5f;
  float ew = (rintf(x2) + 1.0f) * SCALE_F - 0.5f;
  float eh = (rintf(y2) + 1.0f) * SCALE_F - 0.5f;
  float rw = fmaxf(ew - sw, 0.1f);
  float rh = fmaxf(eh - sh, 0.1f);
  float bw = rw / PBIN, bh = rh / PBIN;
  float subw = bw / SSAMP, subh = bh / SSAMP;

  float tx = 0.f, ty = 0.f, mval = 1.f;
  if (MODE == 1) {
    const float* omr = om + (size_t)n * (3*PP);
    tx = omr[p] * TRANS_STD;
    ty = omr[PP + p] * TRANS_STD;
    mval = 1.0f / (1.0f + expf(-omr[2*PP + p]));
  }
  float wstart = pw * bw + sw + tx * rw;
  float hstart = ph * bh + sh + ty * rh;

  int offs[16];
  float wts[16];
  float cnt = 0.f;
  int base_b = b * (HH*WW);
#pragma unroll
  for (int ih = 0; ih < SSAMP; ++ih) {
#pragma unroll
    for (int iw = 0; iw < SSAMP; ++iw) {
      float wv_ = wstart + iw * subw;
      float hv_ = hstart + ih * subh;
      float validf = (wv_ >= -0.5f && wv_ <= WW - 0.5f &&
                      hv_ >= -0.5f && hv_ <= HH - 0.5f) ? 1.f : 0.f;
      cnt += validf;
      float wc = fminf(fmaxf(wv_, 0.f), WW - 1.0f);
      float hc = fminf(fmaxf(hv_, 0.f), HH - 1.0f);
      int x0 = (int)floorf(wc), y0 = (int)floorf(hc);
      int x1i = min(x0 + 1, WW - 1), y1i = min(y0 + 1, HH - 1);
      float lx = wc - (float)x0, ly = hc - (float)y0;
      int s4 = (ih*2 + iw) * 4;
      offs[s4+0] = (base_b + y0 *WW + x0 ) * (CCH/2);
      offs[s4+1] = (base_b + y0 *WW + x1i) * (CCH/2);
      offs[s4+2] = (base_b + y1i*WW + x0 ) * (CCH/2);
      offs[s4+3] = (base_b + y1i*WW + x1i) * (CCH/2);
      wts[s4+0] = validf * (1.f-ly)*(1.f-lx);
      wts[s4+1] = validf * (1.f-ly)*lx;
      wts[s4+2] = validf * ly*(1.f-lx);
      wts[s4+3] = validf * ly*lx;
    }
  }
  float inv = 1.0f / fmaxf(cnt, 1.0f);
  if (MODE == 1) inv *= mval;

  const int cl = lane * 4;
  f32x4 acc = {0.f, 0.f, 0.f, 0.f};
#pragma unroll
  for (int s = 0; s < 16; ++s) {
    u32x2 v = *(const u32x2*)&xt[offs[s] + lane*2];
    acc[0] += wts[s] * bf_lo(v[0]);
    acc[1] += wts[s] * bf_hi(v[0]);
    acc[2] += wts[s] * bf_lo(v[1]);
    acc[3] += wts[s] * bf_hi(v[1]);
  }
  acc *= inv;

  if (MODE == 0) {
    unsigned short* bout = (unsigned short*)outp;
    u32x2 pkd = { pk2(acc[0], acc[1]), pk2(acc[2], acc[3]) };
    *(u32x2*)&bout[(size_t)n*KDIM + p*CCH + cl] = pkd;
  } else {
    *(f32x4*)&lds[wv][cl] = acc;
    __syncthreads();
    float* fout = (float*)outp;
    int c = t;
    f32x4 o = { lds[0][c], lds[1][c], lds[2][c], lds[3][c] };
    *(f32x4*)&fout[(size_t)n*KDIM + (size_t)c*PP + p0] = o;
  }
}

// ---------------- split-K GEMM: partial[s] (bf16) = A(bf16 192xK) * bf16(B) ---
// BM=192, BN=128, BK=32, 8 waves as 4m x 2n (wave tile 48x64). 1D grid NB*S.
// B staged as packed bf16-pair u32 [n][16+2pad]; conversion at staging.
// 1-deep register prefetch; wg_barrier (no vmcnt drain) keeps prefetch alive.
// SWZ=1 (NB==8, S%8==0): same-split n-blocks share one XCD's L2 for A.
template<int PERM, int SWZ>
__global__ __launch_bounds__(512, 4) void gemm_splitk(
    const unsigned* __restrict__ A, int ldAu,
    const float* __restrict__ Bm, int N, int ldB,
    unsigned short* __restrict__ partial, int NB, int S, int chunks)
{
  __shared__ __align__(16) unsigned lds_a[192*20];   // [m][16 u32 + pad4]
  __shared__ __align__(16) unsigned lds_b[128*18];   // [n][16 u32(k-pairs) + pad2]

  int t   = threadIdx.x;
  int bid = blockIdx.x;
  int s, nblk;
  if (SWZ) {            // NB==8, S%8==0, grid%64==0
    int xcd = bid & 7;
    nblk    = (bid >> 3) & 7;
    s       = xcd * (S >> 3) + (bid >> 6);
  } else {
    nblk = bid % NB;
    s    = bid / NB;
  }
  int n0 = nblk * 128;
  int q = chunks / S, r = chunks % S;
  int myc = q + (s < r ? 1 : 0);
  int c0 = s*q + (s < r ? s : r);
  int k0 = c0 * 32;

  int wv = t >> 6, lane = t & 63;
  int wm = wv & 3, wn = wv >> 2;               // 4m x 2n
  int m0w = wm * 48;
  int n0w = wn * 64;
  int lrow = lane & 15, lg = lane >> 4;

  f32x4 acc[3][4];
#pragma unroll
  for (int i = 0; i < 3; ++i)
#pragma unroll
    for (int j = 0; j < 4; ++j) acc[i][j] = {0.f,0.f,0.f,0.f};

  u32x2 areg[3];
  float bv[8];
  const int am  = t >> 3;         // 0..63 (A row within 64-row pass)
  const int akp = (t & 7) * 2;    // u32-pair within 16-u32 row chunk
  const int bn  = t & 127;        // B: n within tile
  const int bk8 = (t >> 7) * 8;   // B: k-base (0,8,16,24)

  auto load_tile = [&](int it) {
    int kg = k0 + it*32;
#pragma unroll
    for (int i = 0; i < 3; ++i) {
      int m = am + i*64;
      areg[i] = *(const u32x2*)&A[(size_t)m*ldAu + (kg>>1) + akp];
    }
    int gn = n0 + bn;
    bool okn = (gn < N);
#pragma unroll
    for (int i = 0; i < 8; ++i) {
      int rr = kg + bk8 + i;
      size_t srow = PERM ? ((size_t)(rr & 255)*PP + (rr >> 8)) : (size_t)rr;
      bv[i] = okn ? Bm[srow*ldB + gn] : 0.f;
    }
  };

  load_tile(0);
  for (int it = 0; it < myc; ++it) {
    wg_barrier();      // readers of prev tile done; prefetch stays in flight
#pragma unroll
    for (int i = 0; i < 3; ++i) {
      int m = am + i*64;
      *(u32x2*)&lds_a[m*20 + akp] = areg[i];
    }
    {
      u32x2 w01 = { pk2(bv[0], bv[1]), pk2(bv[2], bv[3]) };
      u32x2 w23 = { pk2(bv[4], bv[5]), pk2(bv[6], bv[7]) };
      *(u32x2*)&lds_b[bn*18 + (bk8>>1)]     = w01;
      *(u32x2*)&lds_b[bn*18 + (bk8>>1) + 2] = w23;
    }
    wg_barrier();      // lgkmcnt(0) makes LDS writes visible; no vmcnt drain
    if (it + 1 < myc) load_tile(it + 1);      // overlap HBM with compute

    bf16x8 af[3];
#pragma unroll
    for (int mf = 0; mf < 3; ++mf) {
      u32x4 ra = *(const u32x4*)&lds_a[(m0w + mf*16 + lrow)*20 + lg*4];
      af[mf] = __builtin_bit_cast(bf16x8, ra);
    }
    bf16x8 bfrag[4];
#pragma unroll
    for (int nf = 0; nf < 4; ++nf) {
      int col = n0w + nf*16 + lrow;
      u32x2 r0 = *(const u32x2*)&lds_b[col*18 + lg*4];
      u32x2 r1 = *(const u32x2*)&lds_b[col*18 + lg*4 + 2];
      u32x4 ub = { r0[0], r0[1], r1[0], r1[1] };
      bfrag[nf] = __builtin_bit_cast(bf16x8, ub);
    }
#pragma unroll
    for (int nf = 0; nf < 4; ++nf)
#pragma unroll
      for (int mf = 0; mf < 3; ++mf)
        acc[mf][nf] = __builtin_amdgcn_mfma_f32_16x16x32_bf16(af[mf], bfrag[nf], acc[mf][nf], 0, 0, 0);
  }

#pragma unroll
  for (int mf = 0; mf < 3; ++mf) {
#pragma unroll
    for (int nf = 0; nf < 4; ++nf) {
      int gcol = n0 + n0w + nf*16 + lrow;
      if (gcol < N) {
#pragma unroll
        for (int rr = 0; rr < 4; ++rr) {
          int m = m0w + mf*16 + lg*4 + rr;
          partial[((size_t)s*NROIS + m)*N + gcol] = f2bf(acc[mf][nf][rr]);
        }
      }
    }
  }
}

// ------- reduce bf16 partials + bias + relu -> bf16 f (4 vals/thread) ---------
__global__ __launch_bounds__(256) void reduce_kernel(
    const unsigned short* __restrict__ partial, const float* __restrict__ bias,
    unsigned short* __restrict__ outp, int N, int S)
{
  int nn = (blockIdx.x*256 + threadIdx.x) * 4;
  int m  = blockIdx.y;
  if (nn >= N) return;
  f32x4 a = *(const f32x4*)&bias[nn];
  size_t stride = (size_t)NROIS * N;
  const unsigned short* p = &partial[(size_t)m*N + nn];
#pragma unroll 4
  for (int s = 0; s < S; ++s) {
    u32x2 v = *(const u32x2*)&p[(size_t)s*stride];
    a[0] += bf_lo(v[0]); a[1] += bf_hi(v[0]);
    a[2] += bf_lo(v[1]); a[3] += bf_hi(v[1]);
  }
  a[0] = fmaxf(a[0], 0.f); a[1] = fmaxf(a[1], 0.f);
  a[2] = fmaxf(a[2], 0.f); a[3] = fmaxf(a[3], 0.f);
  u32x2 pkd = { pk2(a[0], a[1]), pk2(a[2], a[3]) };
  *(u32x2*)&outp[(size_t)m*N + nn] = pkd;
}

// ------- reduce3: om[n][d] = b3[d] + sum_s p3[s][n][d]  (f32 out, 588 wide) ---
__global__ __launch_bounds__(640) void reduce3_kernel(
    const unsigned short* __restrict__ p3, const float* __restrict__ b3,
    float* __restrict__ om, int S)
{
  int d = threadIdx.x;
  int nn = blockIdx.x;
  if (d >= 3*PP) return;
  float a = b3[d];
#pragma unroll 4
  for (int s = 0; s < S; ++s)
    a += bf_u16(p3[((size_t)s*NROIS + nn)*(3*PP) + d]);
  om[(size_t)nn*(3*PP) + d] = a;
}

extern "C" void kernel_launch(void* const* d_in, const int* in_sizes, int n_in,
                              void* d_out, int out_size, void* d_ws, size_t ws_size,
                              hipStream_t stream)
{
  const float* x    = (const float*)d_in[0];
  const float* rois = (const float*)d_in[1];
  const float* w1   = (const float*)d_in[2];
  const float* b1   = (const float*)d_in[3];
  const float* w2   = (const float*)d_in[4];
  const float* b2   = (const float*)d_in[5];
  const float* w3   = (const float*)d_in[6];
  const float* b3   = (const float*)d_in[7];

  char* ws = (char*)d_ws;
  size_t off = 0;
  unsigned* xt = (unsigned*)(ws + off);               off += (size_t)2*(HH*WW)*(CCH/2)*4;
  unsigned short* base = (unsigned short*)(ws + off); off += (size_t)NROIS*KDIM*2;
  unsigned short* f1 = (unsigned short*)(ws + off);   off += (size_t)NROIS*FCDIM*2;
  unsigned short* f2 = (unsigned short*)(ws + off);   off += (size_t)NROIS*FCDIM*2;
  float* om = (float*)(ws + off);                     off += (size_t)NROIS*(3*PP)*4;
  const int S1 = 64, S2 = 32, S3 = 16;
  unsigned short* partial1 = (unsigned short*)(ws + off); off += (size_t)S1*NROIS*FCDIM*2;  // 25.2MB
  unsigned short* partial2 = (unsigned short*)(ws + off); off += (size_t)S2*NROIS*FCDIM*2;  // 12.6MB
  unsigned short* partial3 = (unsigned short*)(ws + off); off += (size_t)S3*NROIS*(3*PP)*2; // 3.6MB
  (void)ws_size;

  // 1) transpose+bf16 x -> xt
  transpose_x_kernel<<<dim3(512, 8, 2), dim3(32, 8), 0, stream>>>(x, xt);
  // 2) base pool -> bf16 [192, 50176] (k = p*256+c)
  pool_kernel<0><<<dim3(NROIS, PP/4), 256, 0, stream>>>(xt, rois, nullptr, base);
  // 3) f1 = relu(base @ w1 + b1); 1568 K-chunks, 64 splits, XCD-swizzled
  gemm_splitk<1,1><<<8*S1, 512, 0, stream>>>((const unsigned*)base, KDIM/2, w1, FCDIM, FCDIM, partial1, 8, S1, KDIM/32);
  reduce_kernel<<<dim3(1, NROIS), 256, 0, stream>>>(partial1, b1, f1, FCDIM, S1);
  // 4) f2 = relu(f1 @ w2 + b2)
  gemm_splitk<0,1><<<8*S2, 512, 0, stream>>>((const unsigned*)f1, FCDIM/2, w2, FCDIM, FCDIM, partial2, 8, S2, FCDIM/32);
  reduce_kernel<<<dim3(1, NROIS), 256, 0, stream>>>(partial2, b2, f2, FCDIM, S2);
  // 5) partial3 = split-K of f2 @ w3 (N = 588)
  gemm_splitk<0,0><<<5*S3, 512, 0, stream>>>((const unsigned*)f2, FCDIM/2, w3, 3*PP, 3*PP, partial3, 5, S3, FCDIM/32);
  // 5b) om = b3 + sum partial3 (f32)
  reduce3_kernel<<<NROIS, 640, 0, stream>>>(partial3, b3, om, S3);
  // 6) final pool reads om, * sigmoid(mask) -> d_out
  pool_kernel<1><<<dim3(NROIS, PP/4), 256, 0, stream>>>(xt, rois, om, d_out);
}

// Round 12
// 152.310 us; speedup vs baseline: 1.2235x; 1.0652x over previous
//
#include <hip/hip_runtime.h>

#define PBIN 14
#define SSAMP 2
#define SCALE_F 0.0625f
#define TRANS_STD 0.1f
#define CCH 256
#define FCDIM 1024
#define NROIS 192
#define HH 128
#define WW 128
#define PP (PBIN*PBIN)      // 196
#define KDIM (CCH*PP)       // 50176

typedef __bf16 bf16x8 __attribute__((ext_vector_type(8)));
typedef float  f32x4  __attribute__((ext_vector_type(4)));
typedef unsigned u32x4 __attribute__((ext_vector_type(4)));
typedef unsigned u32x2 __attribute__((ext_vector_type(2)));

__device__ __forceinline__ unsigned short f2bf(float f) {
  unsigned u = __builtin_bit_cast(unsigned, f);
  u += 0x7FFFu + ((u >> 16) & 1u);   // RNE
  return (unsigned short)(u >> 16);
}
__device__ __forceinline__ unsigned pk2(float lo, float hi) {
  unsigned ulo = __builtin_bit_cast(unsigned, lo) + 0x8000u;
  unsigned uhi = __builtin_bit_cast(unsigned, hi) + 0x8000u;
  return __builtin_amdgcn_perm(uhi, ulo, 0x07060302u);
}
__device__ __forceinline__ float bf_lo(unsigned u) {
  return __builtin_bit_cast(float, u << 16);
}
__device__ __forceinline__ float bf_hi(unsigned u) {
  return __builtin_bit_cast(float, u & 0xFFFF0000u);
}
__device__ __forceinline__ float bf_u16(unsigned short v) {
  return __builtin_bit_cast(float, (unsigned)v << 16);
}

// Barrier without the vmcnt(0) drain __syncthreads() emits (in-flight global
// prefetch to VGPRs survives; LDS visibility via lgkmcnt(0)).
__device__ __forceinline__ void wg_barrier() {
  asm volatile("s_waitcnt lgkmcnt(0)" ::: "memory");
  __builtin_amdgcn_s_barrier();
  asm volatile("" ::: "memory");
}

// -------- transpose+convert x [B,C,H,W] f32 -> xt [B,H,W,C/2] u32(bf16 pair) --
__global__ __launch_bounds__(256) void transpose_x_kernel(
    const float* __restrict__ x, unsigned* __restrict__ xt)
{
  __shared__ float tile[32][33];
  int tx = threadIdx.x, ty = threadIdx.y;     // (32, 8)
  int hw0 = blockIdx.x * 32;
  int c0  = blockIdx.y * 32;
  int b   = blockIdx.z;
  const float* xb = x + (size_t)b * CCH * HH * WW;
  unsigned* xtb   = xt + (size_t)b * (HH*WW) * (CCH/2);
#pragma unroll
  for (int k = 0; k < 4; ++k)
    tile[ty + k*8][tx] = xb[(size_t)(c0 + ty + k*8) * (HH*WW) + hw0 + tx];
  __syncthreads();
  int l  = ty*32 + tx;
  int cp = l & 15;
  int hr = l >> 4;
#pragma unroll
  for (int k = 0; k < 2; ++k) {
    int row = hr + k*16;
    unsigned pkd = pk2(tile[2*cp][row], tile[2*cp+1][row]);
    xtb[(size_t)(hw0 + row) * (CCH/2) + (c0>>1) + cp] = pkd;
  }
}

// ---------------- PSRoI pool: wave = bin, lane = channel-quad -----------------
// Factorized taps: the 2x2 sub-sample bilinear sum is a tensor product
// (row-weights)x(col-weights); duplicate floor cells are merged per axis so
// loads/bin drop from 16 to nc*nr (typically ~7). All merge branches are
// wave-uniform; all array-free (static indices only).
// MODE 0: base -> bf16 [n][p*256+c]. MODE 1: read om (f32), *sigmoid(mask) -> f32.
template<int MODE>
__global__ __launch_bounds__(256) void pool_kernel(
    const unsigned* __restrict__ xt, const float* __restrict__ rois,
    const float* __restrict__ om, void* __restrict__ outp)
{
  __shared__ float lds[4][256];
  const int t = threadIdx.x;
  const int wv = t >> 6, lane = t & 63;
  const int n  = blockIdx.x;
  const int p0 = blockIdx.y * 4;
  const int p  = p0 + wv;
  const int ph = p / PBIN, pw = p % PBIN;

  float rb_ = rois[n*5 + 0];
  float x1 = rois[n*5 + 1], y1 = rois[n*5 + 2];
  float x2 = rois[n*5 + 3], y2 = rois[n*5 + 4];
  int b = (int)rb_;
  float sw = rintf(x1) * SCALE_F - 0.5f;
  float sh = rintf(y1) * SCALE_F - 0.5f;
  float ew = (rintf(x2) + 1.0f) * SCALE_F - 0.5f;
  float eh = (rintf(y2) + 1.0f) * SCALE_F - 0.5f;
  float rw = fmaxf(ew - sw, 0.1f);
  float rh = fmaxf(eh - sh, 0.1f);
  float bw = rw / PBIN, bh = rh / PBIN;
  float subw = bw / SSAMP, subh = bh / SSAMP;

  float tx = 0.f, ty = 0.f, mval = 1.f;
  if (MODE == 1) {
    const float* omr = om + (size_t)n * (3*PP);
    tx = omr[p] * TRANS_STD;
    ty = omr[PP + p] * TRANS_STD;
    mval = 1.0f / (1.0f + expf(-omr[2*PP + p]));
  }
  float wstart = pw * bw + sw + tx * rw;
  float hstart = ph * bh + sh + ty * rh;

  // ---- X axis: two samples -> merged unique columns (nc in {2,3,4}) ----
  float wva = wstart, wvb = wstart + subw;
  float vxa = (wva >= -0.5f && wva <= WW - 0.5f) ? 1.f : 0.f;
  float vxb = (wvb >= -0.5f && wvb <= WW - 0.5f) ? 1.f : 0.f;
  float wca = fminf(fmaxf(wva, 0.f), WW - 1.0f);
  float wcb = fminf(fmaxf(wvb, 0.f), WW - 1.0f);
  int x0a = (int)floorf(wca), x0b = (int)floorf(wcb);
  int x1a = min(x0a + 1, WW - 1), x1b = min(x0b + 1, WW - 1);
  float lxa = wca - (float)x0a, lxb = wcb - (float)x0b;
  int cx0 = x0a, cx1 = x1a, cx2 = x0b, cx3 = x1b;
  float u0 = vxa*(1.f-lxa), u1 = vxa*lxa, u2 = vxb*(1.f-lxb), u3 = vxb*lxb;
  int nc;
  if (x0a == x0b)      { u0 += u2; u1 += u3; nc = 2; }       // same cell
  else if (x1a == x0b) { u1 += u2; cx2 = x1b; u2 = u3; nc = 3; } // abutting
  else nc = 4;

  // ---- Y axis: same construction (nr in {2,3,4}) ----
  float hva = hstart, hvb = hstart + subh;
  float vya = (hva >= -0.5f && hva <= HH - 0.5f) ? 1.f : 0.f;
  float vyb = (hvb >= -0.5f && hvb <= HH - 0.5f) ? 1.f : 0.f;
  float hca = fminf(fmaxf(hva, 0.f), HH - 1.0f);
  float hcb = fminf(fmaxf(hvb, 0.f), HH - 1.0f);
  int y0a = (int)floorf(hca), y0b = (int)floorf(hcb);
  int y1a = min(y0a + 1, HH - 1), y1b = min(y0b + 1, HH - 1);
  float lya = hca - (float)y0a, lyb = hcb - (float)y0b;
  int ry0 = y0a, ry1 = y1a, ry2 = y0b, ry3 = y1b;
  float e0 = vya*(1.f-lya), e1 = vya*lya, e2 = vyb*(1.f-lyb), e3 = vyb*lyb;
  int nr;
  if (y0a == y0b)      { e0 += e2; e1 += e3; nr = 2; }
  else if (y1a == y0b) { e1 += e2; ry2 = y1b; e2 = e3; nr = 3; }
  else nr = 4;

  float cnt = (vxa + vxb) * (vya + vyb);
  float inv = 1.0f / fmaxf(cnt, 1.0f);
  if (MODE == 1) inv *= mval;

  const int base_b = b * (HH*WW);
  const int lofs = lane * 2;
  f32x4 acc = {0.f, 0.f, 0.f, 0.f};

#define PCOL(CX, WX) {                                            \
    u32x2 v = *(const u32x2*)&xt[rbx + (CX)*(CCH/2)];             \
    float wq = wyr * (WX);                                        \
    acc[0] += wq * bf_lo(v[0]); acc[1] += wq * bf_hi(v[0]);       \
    acc[2] += wq * bf_lo(v[1]); acc[3] += wq * bf_hi(v[1]); }
#define PROW(RY, WY) {                                            \
    int rbx = (base_b + (RY)*WW)*(CCH/2) + lofs;                  \
    float wyr = (WY);                                             \
    PCOL(cx0, u0); PCOL(cx1, u1);                                 \
    if (nc > 2) PCOL(cx2, u2);                                    \
    if (nc > 3) PCOL(cx3, u3); }

  PROW(ry0, e0);
  PROW(ry1, e1);
  if (nr > 2) PROW(ry2, e2);
  if (nr > 3) PROW(ry3, e3);
#undef PROW
#undef PCOL

  acc *= inv;

  const int cl = lane * 4;
  if (MODE == 0) {
    unsigned short* bout = (unsigned short*)outp;
    u32x2 pkd = { pk2(acc[0], acc[1]), pk2(acc[2], acc[3]) };
    *(u32x2*)&bout[(size_t)n*KDIM + p*CCH + cl] = pkd;
  } else {
    *(f32x4*)&lds[wv][cl] = acc;
    __syncthreads();
    float* fout = (float*)outp;
    int c = t;
    f32x4 o = { lds[0][c], lds[1][c], lds[2][c], lds[3][c] };
    *(f32x4*)&fout[(size_t)n*KDIM + (size_t)c*PP + p0] = o;
  }
}

// ---------------- split-K GEMM: partial[s] (bf16) = A(bf16 192xK) * bf16(B) ---
// BM=192, BN=128, BK=32, 8 waves as 4m x 2n (wave tile 48x64). 1D grid NB*S.
// B staged as packed bf16-pair u32 [n][16+2pad]; conversion at staging.
// 1-deep register prefetch; wg_barrier (no vmcnt drain) keeps prefetch alive.
// SWZ=1 (NB==8, S%8==0): same-split n-blocks share one XCD's L2 for A.
template<int PERM, int SWZ>
__global__ __launch_bounds__(512, 4) void gemm_splitk(
    const unsigned* __restrict__ A, int ldAu,
    const float* __restrict__ Bm, int N, int ldB,
    unsigned short* __restrict__ partial, int NB, int S, int chunks)
{
  __shared__ __align__(16) unsigned lds_a[192*20];   // [m][16 u32 + pad4]
  __shared__ __align__(16) unsigned lds_b[128*18];   // [n][16 u32(k-pairs) + pad2]

  int t   = threadIdx.x;
  int bid = blockIdx.x;
  int s, nblk;
  if (SWZ) {            // NB==8, S%8==0, grid%64==0
    int xcd = bid & 7;
    nblk    = (bid >> 3) & 7;
    s       = xcd * (S >> 3) + (bid >> 6);
  } else {
    nblk = bid % NB;
    s    = bid / NB;
  }
  int n0 = nblk * 128;
  int q = chunks / S, r = chunks % S;
  int myc = q + (s < r ? 1 : 0);
  int c0 = s*q + (s < r ? s : r);
  int k0 = c0 * 32;

  int wv = t >> 6, lane = t & 63;
  int wm = wv & 3, wn = wv >> 2;               // 4m x 2n
  int m0w = wm * 48;
  int n0w = wn * 64;
  int lrow = lane & 15, lg = lane >> 4;

  f32x4 acc[3][4];
#pragma unroll
  for (int i = 0; i < 3; ++i)
#pragma unroll
    for (int j = 0; j < 4; ++j) acc[i][j] = {0.f,0.f,0.f,0.f};

  u32x2 areg[3];
  float bv[8];
  const int am  = t >> 3;         // 0..63 (A row within 64-row pass)
  const int akp = (t & 7) * 2;    // u32-pair within 16-u32 row chunk
  const int bn  = t & 127;        // B: n within tile
  const int bk8 = (t >> 7) * 8;   // B: k-base (0,8,16,24)

  auto load_tile = [&](int it) {
    int kg = k0 + it*32;
#pragma unroll
    for (int i = 0; i < 3; ++i) {
      int m = am + i*64;
      areg[i] = *(const u32x2*)&A[(size_t)m*ldAu + (kg>>1) + akp];
    }
    int gn = n0 + bn;
    bool okn = (gn < N);
#pragma unroll
    for (int i = 0; i < 8; ++i) {
      int rr = kg + bk8 + i;
      size_t srow = PERM ? ((size_t)(rr & 255)*PP + (rr >> 8)) : (size_t)rr;
      bv[i] = okn ? Bm[srow*ldB + gn] : 0.f;
    }
  };

  load_tile(0);
  for (int it = 0; it < myc; ++it) {
    wg_barrier();      // readers of prev tile done; prefetch stays in flight
#pragma unroll
    for (int i = 0; i < 3; ++i) {
      int m = am + i*64;
      *(u32x2*)&lds_a[m*20 + akp] = areg[i];
    }
    {
      u32x2 w01 = { pk2(bv[0], bv[1]), pk2(bv[2], bv[3]) };
      u32x2 w23 = { pk2(bv[4], bv[5]), pk2(bv[6], bv[7]) };
      *(u32x2*)&lds_b[bn*18 + (bk8>>1)]     = w01;
      *(u32x2*)&lds_b[bn*18 + (bk8>>1) + 2] = w23;
    }
    wg_barrier();      // lgkmcnt(0) makes LDS writes visible; no vmcnt drain
    if (it + 1 < myc) load_tile(it + 1);      // overlap HBM with compute

    bf16x8 af[3];
#pragma unroll
    for (int mf = 0; mf < 3; ++mf) {
      u32x4 ra = *(const u32x4*)&lds_a[(m0w + mf*16 + lrow)*20 + lg*4];
      af[mf] = __builtin_bit_cast(bf16x8, ra);
    }
    bf16x8 bfrag[4];
#pragma unroll
    for (int nf = 0; nf < 4; ++nf) {
      int col = n0w + nf*16 + lrow;
      u32x2 r0 = *(const u32x2*)&lds_b[col*18 + lg*4];
      u32x2 r1 = *(const u32x2*)&lds_b[col*18 + lg*4 + 2];
      u32x4 ub = { r0[0], r0[1], r1[0], r1[1] };
      bfrag[nf] = __builtin_bit_cast(bf16x8, ub);
    }
#pragma unroll
    for (int nf = 0; nf < 4; ++nf)
#pragma unroll
      for (int mf = 0; mf < 3; ++mf)
        acc[mf][nf] = __builtin_amdgcn_mfma_f32_16x16x32_bf16(af[mf], bfrag[nf], acc[mf][nf], 0, 0, 0);
  }

#pragma unroll
  for (int mf = 0; mf < 3; ++mf) {
#pragma unroll
    for (int nf = 0; nf < 4; ++nf) {
      int gcol = n0 + n0w + nf*16 + lrow;
      if (gcol < N) {
#pragma unroll
        for (int rr = 0; rr < 4; ++rr) {
          int m = m0w + mf*16 + lg*4 + rr;
          partial[((size_t)s*NROIS + m)*N + gcol] = f2bf(acc[mf][nf][rr]);
        }
      }
    }
  }
}

// ------- reduce bf16 partials + bias + relu -> bf16 f (4 vals/thread) ---------
__global__ __launch_bounds__(256) void reduce_kernel(
    const unsigned short* __restrict__ partial, const float* __restrict__ bias,
    unsigned short* __restrict__ outp, int N, int S)
{
  int nn = (blockIdx.x*256 + threadIdx.x) * 4;
  int m  = blockIdx.y;
  if (nn >= N) return;
  f32x4 a = *(const f32x4*)&bias[nn];
  size_t stride = (size_t)NROIS * N;
  const unsigned short* p = &partial[(size_t)m*N + nn];
#pragma unroll 4
  for (int s = 0; s < S; ++s) {
    u32x2 v = *(const u32x2*)&p[(size_t)s*stride];
    a[0] += bf_lo(v[0]); a[1] += bf_hi(v[0]);
    a[2] += bf_lo(v[1]); a[3] += bf_hi(v[1]);
  }
  a[0] = fmaxf(a[0], 0.f); a[1] = fmaxf(a[1], 0.f);
  a[2] = fmaxf(a[2], 0.f); a[3] = fmaxf(a[3], 0.f);
  u32x2 pkd = { pk2(a[0], a[1]), pk2(a[2], a[3]) };
  *(u32x2*)&outp[(size_t)m*N + nn] = pkd;
}

// ------- reduce3: om[n][d] = b3[d] + sum_s p3[s][n][d]  (f32 out, 588 wide) ---
__global__ __launch_bounds__(640) void reduce3_kernel(
    const unsigned short* __restrict__ p3, const float* __restrict__ b3,
    float* __restrict__ om, int S)
{
  int d = threadIdx.x;
  int nn = blockIdx.x;
  if (d >= 3*PP) return;
  float a = b3[d];
#pragma unroll 4
  for (int s = 0; s < S; ++s)
    a += bf_u16(p3[((size_t)s*NROIS + nn)*(3*PP) + d]);
  om[(size_t)nn*(3*PP) + d] = a;
}

extern "C" void kernel_launch(void* const* d_in, const int* in_sizes, int n_in,
                              void* d_out, int out_size, void* d_ws, size_t ws_size,
                              hipStream_t stream)
{
  const float* x    = (const float*)d_in[0];
  const float* rois = (const float*)d_in[1];
  const float* w1   = (const float*)d_in[2];
  const float* b1   = (const float*)d_in[3];
  const float* w2   = (const float*)d_in[4];
  const float* b2   = (const float*)d_in[5];
  const float* w3   = (const float*)d_in[6];
  const float* b3   = (const float*)d_in[7];

  char* ws = (char*)d_ws;
  size_t off = 0;
  unsigned* xt = (unsigned*)(ws + off);               off += (size_t)2*(HH*WW)*(CCH/2)*4;
  unsigned short* base = (unsigned short*)(ws + off); off += (size_t)NROIS*KDIM*2;
  unsigned short* f1 = (unsigned short*)(ws + off);   off += (size_t)NROIS*FCDIM*2;
  unsigned short* f2 = (unsigned short*)(ws + off);   off += (size_t)NROIS*FCDIM*2;
  float* om = (float*)(ws + off);                     off += (size_t)NROIS*(3*PP)*4;
  const int S1 = 64, S2 = 32, S3 = 16;
  unsigned short* partial1 = (unsigned short*)(ws + off); off += (size_t)S1*NROIS*FCDIM*2;  // 25.2MB
  unsigned short* partial2 = (unsigned short*)(ws + off); off += (size_t)S2*NROIS*FCDIM*2;  // 12.6MB
  unsigned short* partial3 = (unsigned short*)(ws + off); off += (size_t)S3*NROIS*(3*PP)*2; // 3.6MB
  (void)ws_size;

  // 1) transpose+bf16 x -> xt
  transpose_x_kernel<<<dim3(512, 8, 2), dim3(32, 8), 0, stream>>>(x, xt);
  // 2) base pool -> bf16 [192, 50176] (k = p*256+c)
  pool_kernel<0><<<dim3(NROIS, PP/4), 256, 0, stream>>>(xt, rois, nullptr, base);
  // 3) f1 = relu(base @ w1 + b1); 1568 K-chunks, 64 splits, XCD-swizzled
  gemm_splitk<1,1><<<8*S1, 512, 0, stream>>>((const unsigned*)base, KDIM/2, w1, FCDIM, FCDIM, partial1, 8, S1, KDIM/32);
  reduce_kernel<<<dim3(1, NROIS), 256, 0, stream>>>(partial1, b1, f1, FCDIM, S1);
  // 4) f2 = relu(f1 @ w2 + b2)
  gemm_splitk<0,1><<<8*S2, 512, 0, stream>>>((const unsigned*)f1, FCDIM/2, w2, FCDIM, FCDIM, partial2, 8, S2, FCDIM/32);
  reduce_kernel<<<dim3(1, NROIS), 256, 0, stream>>>(partial2, b2, f2, FCDIM, S2);
  // 5) partial3 = split-K of f2 @ w3 (N = 588)
  gemm_splitk<0,0><<<5*S3, 512, 0, stream>>>((const unsigned*)f2, FCDIM/2, w3, 3*PP, 3*PP, partial3, 5, S3, FCDIM/32);
  // 5b) om = b3 + sum partial3 (f32)
  reduce3_kernel<<<NROIS, 640, 0, stream>>>(partial3, b3, om, S3);
  // 6) final pool reads om, * sigmoid(mask) -> d_out
  pool_kernel<1><<<dim3(NROIS, PP/4), 256, 0, stream>>>(xt, rois, om, d_out);
}

// Round 13
// 143.643 us; speedup vs baseline: 1.2973x; 1.0603x over previous
//
#include <hip/hip_runtime.h>

#define PBIN 14
#define SSAMP 2
#define SCALE_F 0.0625f
#define TRANS_STD 0.1f
#define CCH 256
#define FCDIM 1024
#define NROIS 192
#define HH 128
#define WW 128
#define PP (PBIN*PBIN)      // 196
#define KDIM (CCH*PP)       // 50176

typedef __bf16 bf16x8 __attribute__((ext_vector_type(8)));
typedef float  f32x4  __attribute__((ext_vector_type(4)));
typedef unsigned u32x4 __attribute__((ext_vector_type(4)));
typedef unsigned u32x2 __attribute__((ext_vector_type(2)));

__device__ __forceinline__ unsigned short f2bf(float f) {
  unsigned u = __builtin_bit_cast(unsigned, f);
  u += 0x7FFFu + ((u >> 16) & 1u);   // RNE
  return (unsigned short)(u >> 16);
}
__device__ __forceinline__ unsigned pk2(float lo, float hi) {
  unsigned ulo = __builtin_bit_cast(unsigned, lo) + 0x8000u;
  unsigned uhi = __builtin_bit_cast(unsigned, hi) + 0x8000u;
  return __builtin_amdgcn_perm(uhi, ulo, 0x07060302u);
}
__device__ __forceinline__ float bf_lo(unsigned u) {
  return __builtin_bit_cast(float, u << 16);
}
__device__ __forceinline__ float bf_hi(unsigned u) {
  return __builtin_bit_cast(float, u & 0xFFFF0000u);
}
__device__ __forceinline__ float bf_u16(unsigned short v) {
  return __builtin_bit_cast(float, (unsigned)v << 16);
}

// Barrier without the vmcnt(0) drain __syncthreads() emits.
__device__ __forceinline__ void wg_barrier() {
  asm volatile("s_waitcnt lgkmcnt(0)" ::: "memory");
  __builtin_amdgcn_s_barrier();
  asm volatile("" ::: "memory");
}

// -------- transpose+convert x [B,C,H,W] f32 -> xt [B,H,W,C/2] u32(bf16 pair) --
__global__ __launch_bounds__(256) void transpose_x_kernel(
    const float* __restrict__ x, unsigned* __restrict__ xt)
{
  __shared__ float tile[32][33];
  int tx = threadIdx.x, ty = threadIdx.y;     // (32, 8)
  int hw0 = blockIdx.x * 32;
  int c0  = blockIdx.y * 32;
  int b   = blockIdx.z;
  const float* xb = x + (size_t)b * CCH * HH * WW;
  unsigned* xtb   = xt + (size_t)b * (HH*WW) * (CCH/2);
#pragma unroll
  for (int k = 0; k < 4; ++k)
    tile[ty + k*8][tx] = xb[(size_t)(c0 + ty + k*8) * (HH*WW) + hw0 + tx];
  __syncthreads();
  int l  = ty*32 + tx;
  int cp = l & 15;
  int hr = l >> 4;
#pragma unroll
  for (int k = 0; k < 2; ++k) {
    int row = hr + k*16;
    unsigned pkd = pk2(tile[2*cp][row], tile[2*cp+1][row]);
    xtb[(size_t)(hw0 + row) * (CCH/2) + (c0>>1) + cp] = pkd;
  }
}

// ---------------- PSRoI pool: HALF-WAVE = bin, lane = channel-oct -------------
// Block = 4 waves = 8 bins; half-wave h owns bin p0+2*wv+h, its 32 lanes load
// u32x4 (8 ch / 16B) per tap. Factorized 2x2 taps (merged unique rows/cols).
// Per-bin geometry cost and tap instruction count are both halved vs r12.
// MODE 0: base -> bf16 [n][p*256+c]. MODE 1: read om (f32), *sigmoid(mask) -> f32.
template<int MODE>
__global__ __launch_bounds__(256) void pool_kernel(
    const unsigned* __restrict__ xt, const float* __restrict__ rois,
    const float* __restrict__ om, void* __restrict__ outp)
{
  __shared__ float lds[8][256];
  const int t = threadIdx.x;
  const int wv = t >> 6, lane = t & 63;
  const int h  = lane >> 5;       // bin half
  const int j  = lane & 31;       // channel-oct (8 ch)
  const int n  = blockIdx.x;
  const int p0 = blockIdx.y * 8;
  const int p  = p0 + wv*2 + h;   // this half-wave's bin (may be >= PP in tail)
  const bool pok = (p < PP);
  const int pc = pok ? p : 0;     // safe index for om reads
  const int ph = p / PBIN, pw = p % PBIN;

  float rb_ = rois[n*5 + 0];
  float x1 = rois[n*5 + 1], y1 = rois[n*5 + 2];
  float x2 = rois[n*5 + 3], y2 = rois[n*5 + 4];
  int b = (int)rb_;
  float sw = rintf(x1) * SCALE_F - 0.5f;
  float sh = rintf(y1) * SCALE_F - 0.5f;
  float ew = (rintf(x2) + 1.0f) * SCALE_F - 0.5f;
  float eh = (rintf(y2) + 1.0f) * SCALE_F - 0.5f;
  float rw = fmaxf(ew - sw, 0.1f);
  float rh = fmaxf(eh - sh, 0.1f);
  float bw = rw / PBIN, bh = rh / PBIN;
  float subw = bw / SSAMP, subh = bh / SSAMP;

  float tx = 0.f, ty = 0.f, mval = 1.f;
  if (MODE == 1) {
    const float* omr = om + (size_t)n * (3*PP);
    tx = omr[pc] * TRANS_STD;
    ty = omr[PP + pc] * TRANS_STD;
    mval = 1.0f / (1.0f + expf(-omr[2*PP + pc]));
  }
  float wstart = pw * bw + sw + tx * rw;
  float hstart = ph * bh + sh + ty * rh;

  // ---- X axis: two samples -> merged unique columns (nc in {2,3,4}) ----
  float wva = wstart, wvb = wstart + subw;
  float vxa = (wva >= -0.5f && wva <= WW - 0.5f) ? 1.f : 0.f;
  float vxb = (wvb >= -0.5f && wvb <= WW - 0.5f) ? 1.f : 0.f;
  float wca = fminf(fmaxf(wva, 0.f), WW - 1.0f);
  float wcb = fminf(fmaxf(wvb, 0.f), WW - 1.0f);
  int x0a = (int)floorf(wca), x0b = (int)floorf(wcb);
  int x1a = min(x0a + 1, WW - 1), x1b = min(x0b + 1, WW - 1);
  float lxa = wca - (float)x0a, lxb = wcb - (float)x0b;
  int cx0 = x0a, cx1 = x1a, cx2 = x0b, cx3 = x1b;
  float u0 = vxa*(1.f-lxa), u1 = vxa*lxa, u2 = vxb*(1.f-lxb), u3 = vxb*lxb;
  int nc;
  if (x0a == x0b)      { u0 += u2; u1 += u3; nc = 2; }
  else if (x1a == x0b) { u1 += u2; cx2 = x1b; u2 = u3; nc = 3; }
  else nc = 4;

  // ---- Y axis ----
  float hva = hstart, hvb = hstart + subh;
  float vya = (hva >= -0.5f && hva <= HH - 0.5f) ? 1.f : 0.f;
  float vyb = (hvb >= -0.5f && hvb <= HH - 0.5f) ? 1.f : 0.f;
  float hca = fminf(fmaxf(hva, 0.f), HH - 1.0f);
  float hcb = fminf(fmaxf(hvb, 0.f), HH - 1.0f);
  int y0a = (int)floorf(hca), y0b = (int)floorf(hcb);
  int y1a = min(y0a + 1, HH - 1), y1b = min(y0b + 1, HH - 1);
  float lya = hca - (float)y0a, lyb = hcb - (float)y0b;
  int ry0 = y0a, ry1 = y1a, ry2 = y0b, ry3 = y1b;
  float e0 = vya*(1.f-lya), e1 = vya*lya, e2 = vyb*(1.f-lyb), e3 = vyb*lyb;
  int nr;
  if (y0a == y0b)      { e0 += e2; e1 += e3; nr = 2; }
  else if (y1a == y0b) { e1 += e2; ry2 = y1b; e2 = e3; nr = 3; }
  else nr = 4;

  float cnt = (vxa + vxb) * (vya + vyb);
  float inv = 1.0f / fmaxf(cnt, 1.0f);
  if (MODE == 1) inv *= mval;

  const int base_b = b * (HH*WW);
  const int lofs = j * 4;          // u32 offset: 8 channels per lane
  f32x4 a01 = {0.f,0.f,0.f,0.f}, a23 = {0.f,0.f,0.f,0.f};

#define PCOL(CX, WX) {                                            \
    u32x4 v = *(const u32x4*)&xt[rbx + (CX)*(CCH/2)];             \
    float wq = wyr * (WX);                                        \
    a01[0] += wq * bf_lo(v[0]); a01[1] += wq * bf_hi(v[0]);       \
    a01[2] += wq * bf_lo(v[1]); a01[3] += wq * bf_hi(v[1]);       \
    a23[0] += wq * bf_lo(v[2]); a23[1] += wq * bf_hi(v[2]);       \
    a23[2] += wq * bf_lo(v[3]); a23[3] += wq * bf_hi(v[3]); }
#define PROW(RY, WY) {                                            \
    int rbx = (base_b + (RY)*WW)*(CCH/2) + lofs;                  \
    float wyr = (WY);                                             \
    PCOL(cx0, u0); PCOL(cx1, u1);                                 \
    if (nc > 2) PCOL(cx2, u2);                                    \
    if (nc > 3) PCOL(cx3, u3); }

  PROW(ry0, e0);
  PROW(ry1, e1);
  if (nr > 2) PROW(ry2, e2);
  if (nr > 3) PROW(ry3, e3);
#undef PROW
#undef PCOL

  a01 *= inv;
  a23 *= inv;

  if (MODE == 0) {
    if (pok) {
      unsigned short* bout = (unsigned short*)outp;
      u32x4 pkd = { pk2(a01[0], a01[1]), pk2(a01[2], a01[3]),
                    pk2(a23[0], a23[1]), pk2(a23[2], a23[3]) };
      *(u32x4*)&bout[(size_t)n*KDIM + p*CCH + j*8] = pkd;   // 16B/lane coalesced
    }
  } else {
    int bin = wv*2 + h;
    *(f32x4*)&lds[bin][j*8]     = a01;
    *(f32x4*)&lds[bin][j*8 + 4] = a23;
    __syncthreads();
    float* fout = (float*)outp;
    int c = t;
    f32x4 o0 = { lds[0][c], lds[1][c], lds[2][c], lds[3][c] };
    size_t ob = (size_t)n*KDIM + (size_t)c*PP + p0;
    *(f32x4*)&fout[ob] = o0;
    if (p0 + 8 <= PP) {            // tail block (p0=192) has only 4 valid p
      f32x4 o1 = { lds[4][c], lds[5][c], lds[6][c], lds[7][c] };
      *(f32x4*)&fout[ob + 4] = o1;
    }
  }
}

// ---------------- split-K GEMM: partial[s] (bf16) = A(bf16 192xK) * bf16(B) ---
// BM=192, BN=128, BK=32, 8 waves as 4m x 2n (wave tile 48x64). 1D grid NB*S.
// B staged as packed bf16-pair u32 [n][16+2pad]; conversion at staging.
// 1-deep register prefetch; wg_barrier (no vmcnt drain) keeps prefetch alive.
// SWZ=1 (NB==8, S%8==0): same-split n-blocks share one XCD's L2 for A.
template<int PERM, int SWZ>
__global__ __launch_bounds__(512, 4) void gemm_splitk(
    const unsigned* __restrict__ A, int ldAu,
    const float* __restrict__ Bm, int N, int ldB,
    unsigned short* __restrict__ partial, int NB, int S, int chunks)
{
  __shared__ __align__(16) unsigned lds_a[192*20];   // [m][16 u32 + pad4]
  __shared__ __align__(16) unsigned lds_b[128*18];   // [n][16 u32(k-pairs) + pad2]

  int t   = threadIdx.x;
  int bid = blockIdx.x;
  int s, nblk;
  if (SWZ) {            // NB==8, S%8==0, grid%64==0
    int xcd = bid & 7;
    nblk    = (bid >> 3) & 7;
    s       = xcd * (S >> 3) + (bid >> 6);
  } else {
    nblk = bid % NB;
    s    = bid / NB;
  }
  int n0 = nblk * 128;
  int q = chunks / S, r = chunks % S;
  int myc = q + (s < r ? 1 : 0);
  int c0 = s*q + (s < r ? s : r);
  int k0 = c0 * 32;

  int wv = t >> 6, lane = t & 63;
  int wm = wv & 3, wn = wv >> 2;               // 4m x 2n
  int m0w = wm * 48;
  int n0w = wn * 64;
  int lrow = lane & 15, lg = lane >> 4;

  f32x4 acc[3][4];
#pragma unroll
  for (int i = 0; i < 3; ++i)
#pragma unroll
    for (int j = 0; j < 4; ++j) acc[i][j] = {0.f,0.f,0.f,0.f};

  u32x2 areg[3];
  float bv[8];
  const int am  = t >> 3;         // 0..63 (A row within 64-row pass)
  const int akp = (t & 7) * 2;    // u32-pair within 16-u32 row chunk
  const int bn  = t & 127;        // B: n within tile
  const int bk8 = (t >> 7) * 8;   // B: k-base (0,8,16,24)

  auto load_tile = [&](int it) {
    int kg = k0 + it*32;
#pragma unroll
    for (int i = 0; i < 3; ++i) {
      int m = am + i*64;
      areg[i] = *(const u32x2*)&A[(size_t)m*ldAu + (kg>>1) + akp];
    }
    int gn = n0 + bn;
    bool okn = (gn < N);
#pragma unroll
    for (int i = 0; i < 8; ++i) {
      int rr = kg + bk8 + i;
      size_t srow = PERM ? ((size_t)(rr & 255)*PP + (rr >> 8)) : (size_t)rr;
      bv[i] = okn ? Bm[srow*ldB + gn] : 0.f;
    }
  };

  load_tile(0);
  for (int it = 0; it < myc; ++it) {
    wg_barrier();      // readers of prev tile done; prefetch stays in flight
#pragma unroll
    for (int i = 0; i < 3; ++i) {
      int m = am + i*64;
      *(u32x2*)&lds_a[m*20 + akp] = areg[i];
    }
    {
      u32x2 w01 = { pk2(bv[0], bv[1]), pk2(bv[2], bv[3]) };
      u32x2 w23 = { pk2(bv[4], bv[5]), pk2(bv[6], bv[7]) };
      *(u32x2*)&lds_b[bn*18 + (bk8>>1)]     = w01;
      *(u32x2*)&lds_b[bn*18 + (bk8>>1) + 2] = w23;
    }
    wg_barrier();      // lgkmcnt(0) makes LDS writes visible; no vmcnt drain
    if (it + 1 < myc) load_tile(it + 1);      // overlap HBM with compute

    bf16x8 af[3];
#pragma unroll
    for (int mf = 0; mf < 3; ++mf) {
      u32x4 ra = *(const u32x4*)&lds_a[(m0w + mf*16 + lrow)*20 + lg*4];
      af[mf] = __builtin_bit_cast(bf16x8, ra);
    }
    bf16x8 bfrag[4];
#pragma unroll
    for (int nf = 0; nf < 4; ++nf) {
      int col = n0w + nf*16 + lrow;
      u32x2 r0 = *(const u32x2*)&lds_b[col*18 + lg*4];
      u32x2 r1 = *(const u32x2*)&lds_b[col*18 + lg*4 + 2];
      u32x4 ub = { r0[0], r0[1], r1[0], r1[1] };
      bfrag[nf] = __builtin_bit_cast(bf16x8, ub);
    }
#pragma unroll
    for (int nf = 0; nf < 4; ++nf)
#pragma unroll
      for (int mf = 0; mf < 3; ++mf)
        acc[mf][nf] = __builtin_amdgcn_mfma_f32_16x16x32_bf16(af[mf], bfrag[nf], acc[mf][nf], 0, 0, 0);
  }

#pragma unroll
  for (int mf = 0; mf < 3; ++mf) {
#pragma unroll
    for (int nf = 0; nf < 4; ++nf) {
      int gcol = n0 + n0w + nf*16 + lrow;
      if (gcol < N) {
#pragma unroll
        for (int rr = 0; rr < 4; ++rr) {
          int m = m0w + mf*16 + lg*4 + rr;
          partial[((size_t)s*NROIS + m)*N + gcol] = f2bf(acc[mf][nf][rr]);
        }
      }
    }
  }
}

// ------- reduce bf16 partials + bias + relu -> bf16 f (4 vals/thread) ---------
__global__ __launch_bounds__(256) void reduce_kernel(
    const unsigned short* __restrict__ partial, const float* __restrict__ bias,
    unsigned short* __restrict__ outp, int N, int S)
{
  int nn = (blockIdx.x*256 + threadIdx.x) * 4;
  int m  = blockIdx.y;
  if (nn >= N) return;
  f32x4 a = *(const f32x4*)&bias[nn];
  size_t stride = (size_t)NROIS * N;
  const unsigned short* p = &partial[(size_t)m*N + nn];
#pragma unroll 4
  for (int s = 0; s < S; ++s) {
    u32x2 v = *(const u32x2*)&p[(size_t)s*stride];
    a[0] += bf_lo(v[0]); a[1] += bf_hi(v[0]);
    a[2] += bf_lo(v[1]); a[3] += bf_hi(v[1]);
  }
  a[0] = fmaxf(a[0], 0.f); a[1] = fmaxf(a[1], 0.f);
  a[2] = fmaxf(a[2], 0.f); a[3] = fmaxf(a[3], 0.f);
  u32x2 pkd = { pk2(a[0], a[1]), pk2(a[2], a[3]) };
  *(u32x2*)&outp[(size_t)m*N + nn] = pkd;
}

// ------- reduce3: om[n][d] = b3[d] + sum_s p3[s][n][d]  (f32 out, 588 wide) ---
__global__ __launch_bounds__(640) void reduce3_kernel(
    const unsigned short* __restrict__ p3, const float* __restrict__ b3,
    float* __restrict__ om, int S)
{
  int d = threadIdx.x;
  int nn = blockIdx.x;
  if (d >= 3*PP) return;
  float a = b3[d];
#pragma unroll 4
  for (int s = 0; s < S; ++s)
    a += bf_u16(p3[((size_t)s*NROIS + nn)*(3*PP) + d]);
  om[(size_t)nn*(3*PP) + d] = a;
}

extern "C" void kernel_launch(void* const* d_in, const int* in_sizes, int n_in,
                              void* d_out, int out_size, void* d_ws, size_t ws_size,
                              hipStream_t stream)
{
  const float* x    = (const float*)d_in[0];
  const float* rois = (const float*)d_in[1];
  const float* w1   = (const float*)d_in[2];
  const float* b1   = (const float*)d_in[3];
  const float* w2   = (const float*)d_in[4];
  const float* b2   = (const float*)d_in[5];
  const float* w3   = (const float*)d_in[6];
  const float* b3   = (const float*)d_in[7];

  char* ws = (char*)d_ws;
  size_t off = 0;
  unsigned* xt = (unsigned*)(ws + off);               off += (size_t)2*(HH*WW)*(CCH/2)*4;
  unsigned short* base = (unsigned short*)(ws + off); off += (size_t)NROIS*KDIM*2;
  unsigned short* f1 = (unsigned short*)(ws + off);   off += (size_t)NROIS*FCDIM*2;
  unsigned short* f2 = (unsigned short*)(ws + off);   off += (size_t)NROIS*FCDIM*2;
  float* om = (float*)(ws + off);                     off += (size_t)NROIS*(3*PP)*4;
  const int S1 = 64, S2 = 32, S3 = 16;
  unsigned short* partial1 = (unsigned short*)(ws + off); off += (size_t)S1*NROIS*FCDIM*2;  // 25.2MB
  unsigned short* partial2 = (unsigned short*)(ws + off); off += (size_t)S2*NROIS*FCDIM*2;  // 12.6MB
  unsigned short* partial3 = (unsigned short*)(ws + off); off += (size_t)S3*NROIS*(3*PP)*2; // 3.6MB
  (void)ws_size;

  const int PBLK = (PP + 7) / 8;   // 25 bin-groups of 8

  // 1) transpose+bf16 x -> xt
  transpose_x_kernel<<<dim3(512, 8, 2), dim3(32, 8), 0, stream>>>(x, xt);
  // 2) base pool -> bf16 [192, 50176] (k = p*256+c)
  pool_kernel<0><<<dim3(NROIS, PBLK), 256, 0, stream>>>(xt, rois, nullptr, base);
  // 3) f1 = relu(base @ w1 + b1); 1568 K-chunks, 64 splits, XCD-swizzled
  gemm_splitk<1,1><<<8*S1, 512, 0, stream>>>((const unsigned*)base, KDIM/2, w1, FCDIM, FCDIM, partial1, 8, S1, KDIM/32);
  reduce_kernel<<<dim3(1, NROIS), 256, 0, stream>>>(partial1, b1, f1, FCDIM, S1);
  // 4) f2 = relu(f1 @ w2 + b2)
  gemm_splitk<0,1><<<8*S2, 512, 0, stream>>>((const unsigned*)f1, FCDIM/2, w2, FCDIM, FCDIM, partial2, 8, S2, FCDIM/32);
  reduce_kernel<<<dim3(1, NROIS), 256, 0, stream>>>(partial2, b2, f2, FCDIM, S2);
  // 5) partial3 = split-K of f2 @ w3 (N = 588)
  gemm_splitk<0,0><<<5*S3, 512, 0, stream>>>((const unsigned*)f2, FCDIM/2, w3, 3*PP, 3*PP, partial3, 5, S3, FCDIM/32);
  // 5b) om = b3 + sum partial3 (f32)
  reduce3_kernel<<<NROIS, 640, 0, stream>>>(partial3, b3, om, S3);
  // 6) final pool reads om, * sigmoid(mask) -> d_out
  pool_kernel<1><<<dim3(NROIS, PBLK), 256, 0, stream>>>(xt, rois, om, d_out);
}

// Round 14
// 143.532 us; speedup vs baseline: 1.2983x; 1.0008x over previous
//
#include <hip/hip_runtime.h>

#define PBIN 14
#define SSAMP 2
#define SCALE_F 0.0625f
#define TRANS_STD 0.1f
#define CCH 256
#define FCDIM 1024
#define NROIS 192
#define HH 128
#define WW 128
#define PP (PBIN*PBIN)      // 196
#define KDIM (CCH*PP)       // 50176

typedef __bf16 bf16x8 __attribute__((ext_vector_type(8)));
typedef float  f32x4  __attribute__((ext_vector_type(4)));
typedef unsigned u32x4 __attribute__((ext_vector_type(4)));
typedef unsigned u32x2 __attribute__((ext_vector_type(2)));

__device__ __forceinline__ unsigned short f2bf(float f) {
  unsigned u = __builtin_bit_cast(unsigned, f);
  u += 0x7FFFu + ((u >> 16) & 1u);   // RNE
  return (unsigned short)(u >> 16);
}
__device__ __forceinline__ unsigned pk2(float lo, float hi) {
  unsigned ulo = __builtin_bit_cast(unsigned, lo) + 0x8000u;
  unsigned uhi = __builtin_bit_cast(unsigned, hi) + 0x8000u;
  return __builtin_amdgcn_perm(uhi, ulo, 0x07060302u);
}
__device__ __forceinline__ float bf_lo(unsigned u) {
  return __builtin_bit_cast(float, u << 16);
}
__device__ __forceinline__ float bf_hi(unsigned u) {
  return __builtin_bit_cast(float, u & 0xFFFF0000u);
}
__device__ __forceinline__ float bf_u16(unsigned short v) {
  return __builtin_bit_cast(float, (unsigned)v << 16);
}

// Barrier without the vmcnt(0) drain __syncthreads() emits.
__device__ __forceinline__ void wg_barrier() {
  asm volatile("s_waitcnt lgkmcnt(0)" ::: "memory");
  __builtin_amdgcn_s_barrier();
  asm volatile("" ::: "memory");
}

// -------- transpose+convert x [B,C,H,W] f32 -> xt [B,H,W,C/2] u32(bf16 pair) --
// v2: 128c x 64hw tile per block (1024 blocks). Loads: f32x4/thread, 256B wave
// segments. Stores: u32x4/thread, 256B wave segments. LDS [128][65]: write
// 4xb32 2-way (free), read 8xb32 4-way (1.58x, off critical path — BW-bound).
__global__ __launch_bounds__(256) void transpose_x_kernel(
    const float* __restrict__ x, unsigned* __restrict__ xt)
{
  __shared__ float tile[128][65];
  const int t   = threadIdx.x;
  const int hw0 = blockIdx.x * 64;
  const int c0  = blockIdx.y * 128;
  const int b   = blockIdx.z;
  const float* xb = x + (size_t)b * CCH * (HH*WW);
  unsigned* xtb   = xt + (size_t)b * (HH*WW) * (CCH/2);

#pragma unroll
  for (int i = 0; i < 8; ++i) {
    int v    = t + i*256;        // 0..2047
    int crow = v >> 4;           // 0..127
    int hwc  = (v & 15) * 4;     // 0..60
    f32x4 d = *(const f32x4*)&xb[(size_t)(c0 + crow)*(HH*WW) + hw0 + hwc];
    tile[crow][hwc+0] = d[0];
    tile[crow][hwc+1] = d[1];
    tile[crow][hwc+2] = d[2];
    tile[crow][hwc+3] = d[3];
  }
  __syncthreads();
#pragma unroll
  for (int i = 0; i < 4; ++i) {
    int w   = t + i*256;         // 0..1023
    int row = w >> 4;            // 0..63 (hw within tile)
    int q   = w & 15;            // 16B channel-group
    u32x4 o = { pk2(tile[8*q+0][row], tile[8*q+1][row]),
                pk2(tile[8*q+2][row], tile[8*q+3][row]),
                pk2(tile[8*q+4][row], tile[8*q+5][row]),
                pk2(tile[8*q+6][row], tile[8*q+7][row]) };
    *(u32x4*)&xtb[(size_t)(hw0 + row)*(CCH/2) + (c0>>1) + 4*q] = o;
  }
}

// ---------------- PSRoI pool: HALF-WAVE = bin, lane = channel-oct -------------
// Block = 4 waves = 8 bins; half-wave h owns bin p0+2*wv+h, its 32 lanes load
// u32x4 (8 ch / 16B) per tap. Factorized 2x2 taps (merged unique rows/cols).
// __launch_bounds__(256,8) pins VGPR<=64 (m69 occupancy cliff — r8 lesson).
// MODE 0: base -> bf16 [n][p*256+c]. MODE 1: read om (f32), *sigmoid(mask) -> f32.
template<int MODE>
__global__ __launch_bounds__(256, 8) void pool_kernel(
    const unsigned* __restrict__ xt, const float* __restrict__ rois,
    const float* __restrict__ om, void* __restrict__ outp)
{
  __shared__ float lds[8][256];
  const int t = threadIdx.x;
  const int wv = t >> 6, lane = t & 63;
  const int h  = lane >> 5;       // bin half
  const int j  = lane & 31;       // channel-oct (8 ch)
  const int n  = blockIdx.x;
  const int p0 = blockIdx.y * 8;
  const int p  = p0 + wv*2 + h;   // this half-wave's bin (may be >= PP in tail)
  const bool pok = (p < PP);
  const int pc = pok ? p : 0;     // safe index for om reads
  const int ph = p / PBIN, pw = p % PBIN;

  float rb_ = rois[n*5 + 0];
  float x1 = rois[n*5 + 1], y1 = rois[n*5 + 2];
  float x2 = rois[n*5 + 3], y2 = rois[n*5 + 4];
  int b = (int)rb_;
  float sw = rintf(x1) * SCALE_F - 0.5f;
  float sh = rintf(y1) * SCALE_F - 0.5f;
  float ew = (rintf(x2) + 1.0f) * SCALE_F - 0.5f;
  float eh = (rintf(y2) + 1.0f) * SCALE_F - 0.5f;
  float rw = fmaxf(ew - sw, 0.1f);
  float rh = fmaxf(eh - sh, 0.1f);
  float bw = rw / PBIN, bh = rh / PBIN;
  float subw = bw / SSAMP, subh = bh / SSAMP;

  float tx = 0.f, ty = 0.f, mval = 1.f;
  if (MODE == 1) {
    const float* omr = om + (size_t)n * (3*PP);
    tx = omr[pc] * TRANS_STD;
    ty = omr[PP + pc] * TRANS_STD;
    mval = 1.0f / (1.0f + expf(-omr[2*PP + pc]));
  }
  float wstart = pw * bw + sw + tx * rw;
  float hstart = ph * bh + sh + ty * rh;

  // ---- X axis: two samples -> merged unique columns (nc in {2,3,4}) ----
  float wva = wstart, wvb = wstart + subw;
  float vxa = (wva >= -0.5f && wva <= WW - 0.5f) ? 1.f : 0.f;
  float vxb = (wvb >= -0.5f && wvb <= WW - 0.5f) ? 1.f : 0.f;
  float wca = fminf(fmaxf(wva, 0.f), WW - 1.0f);
  float wcb = fminf(fmaxf(wvb, 0.f), WW - 1.0f);
  int x0a = (int)floorf(wca), x0b = (int)floorf(wcb);
  int x1a = min(x0a + 1, WW - 1), x1b = min(x0b + 1, WW - 1);
  float lxa = wca - (float)x0a, lxb = wcb - (float)x0b;
  int cx0 = x0a, cx1 = x1a, cx2 = x0b, cx3 = x1b;
  float u0 = vxa*(1.f-lxa), u1 = vxa*lxa, u2 = vxb*(1.f-lxb), u3 = vxb*lxb;
  int nc;
  if (x0a == x0b)      { u0 += u2; u1 += u3; nc = 2; }
  else if (x1a == x0b) { u1 += u2; cx2 = x1b; u2 = u3; nc = 3; }
  else nc = 4;

  // ---- Y axis ----
  float hva = hstart, hvb = hstart + subh;
  float vya = (hva >= -0.5f && hva <= HH - 0.5f) ? 1.f : 0.f;
  float vyb = (hvb >= -0.5f && hvb <= HH - 0.5f) ? 1.f : 0.f;
  float hca = fminf(fmaxf(hva, 0.f), HH - 1.0f);
  float hcb = fminf(fmaxf(hvb, 0.f), HH - 1.0f);
  int y0a = (int)floorf(hca), y0b = (int)floorf(hcb);
  int y1a = min(y0a + 1, HH - 1), y1b = min(y0b + 1, HH - 1);
  float lya = hca - (float)y0a, lyb = hcb - (float)y0b;
  int ry0 = y0a, ry1 = y1a, ry2 = y0b, ry3 = y1b;
  float e0 = vya*(1.f-lya), e1 = vya*lya, e2 = vyb*(1.f-lyb), e3 = vyb*lyb;
  int nr;
  if (y0a == y0b)      { e0 += e2; e1 += e3; nr = 2; }
  else if (y1a == y0b) { e1 += e2; ry2 = y1b; e2 = e3; nr = 3; }
  else nr = 4;

  float cnt = (vxa + vxb) * (vya + vyb);
  float inv = 1.0f / fmaxf(cnt, 1.0f);
  if (MODE == 1) inv *= mval;

  const int base_b = b * (HH*WW);
  const int lofs = j * 4;          // u32 offset: 8 channels per lane
  f32x4 a01 = {0.f,0.f,0.f,0.f}, a23 = {0.f,0.f,0.f,0.f};

#define PCOL(CX, WX) {                                            \
    u32x4 v = *(const u32x4*)&xt[rbx + (CX)*(CCH/2)];             \
    float wq = wyr * (WX);                                        \
    a01[0] += wq * bf_lo(v[0]); a01[1] += wq * bf_hi(v[0]);       \
    a01[2] += wq * bf_lo(v[1]); a01[3] += wq * bf_hi(v[1]);       \
    a23[0] += wq * bf_lo(v[2]); a23[1] += wq * bf_hi(v[2]);       \
    a23[2] += wq * bf_lo(v[3]); a23[3] += wq * bf_hi(v[3]); }
#define PROW(RY, WY) {                                            \
    int rbx = (base_b + (RY)*WW)*(CCH/2) + lofs;                  \
    float wyr = (WY);                                             \
    PCOL(cx0, u0); PCOL(cx1, u1);                                 \
    if (nc > 2) PCOL(cx2, u2);                                    \
    if (nc > 3) PCOL(cx3, u3); }

  PROW(ry0, e0);
  PROW(ry1, e1);
  if (nr > 2) PROW(ry2, e2);
  if (nr > 3) PROW(ry3, e3);
#undef PROW
#undef PCOL

  a01 *= inv;
  a23 *= inv;

  if (MODE == 0) {
    if (pok) {
      unsigned short* bout = (unsigned short*)outp;
      u32x4 pkd = { pk2(a01[0], a01[1]), pk2(a01[2], a01[3]),
                    pk2(a23[0], a23[1]), pk2(a23[2], a23[3]) };
      *(u32x4*)&bout[(size_t)n*KDIM + p*CCH + j*8] = pkd;   // 16B/lane coalesced
    }
  } else {
    int bin = wv*2 + h;
    *(f32x4*)&lds[bin][j*8]     = a01;
    *(f32x4*)&lds[bin][j*8 + 4] = a23;
    __syncthreads();
    float* fout = (float*)outp;
    int c = t;
    f32x4 o0 = { lds[0][c], lds[1][c], lds[2][c], lds[3][c] };
    size_t ob = (size_t)n*KDIM + (size_t)c*PP + p0;
    *(f32x4*)&fout[ob] = o0;
    if (p0 + 8 <= PP) {            // tail block (p0=192) has only 4 valid p
      f32x4 o1 = { lds[4][c], lds[5][c], lds[6][c], lds[7][c] };
      *(f32x4*)&fout[ob + 4] = o1;
    }
  }
}

// ---------------- split-K GEMM: partial[s] (bf16) = A(bf16 192xK) * bf16(B) ---
// BM=192, BN=128, BK=32, 8 waves as 4m x 2n (wave tile 48x64). 1D grid NB*S.
// B staged as packed bf16-pair u32 [n][16+2pad]; conversion at staging.
// 1-deep register prefetch; wg_barrier (no vmcnt drain) keeps prefetch alive.
// SWZ=1 (NB==8, S%8==0): same-split n-blocks share one XCD's L2 for A.
template<int PERM, int SWZ>
__global__ __launch_bounds__(512, 4) void gemm_splitk(
    const unsigned* __restrict__ A, int ldAu,
    const float* __restrict__ Bm, int N, int ldB,
    unsigned short* __restrict__ partial, int NB, int S, int chunks)
{
  __shared__ __align__(16) unsigned lds_a[192*20];   // [m][16 u32 + pad4]
  __shared__ __align__(16) unsigned lds_b[128*18];   // [n][16 u32(k-pairs) + pad2]

  int t   = threadIdx.x;
  int bid = blockIdx.x;
  int s, nblk;
  if (SWZ) {            // NB==8, S%8==0, grid%64==0
    int xcd = bid & 7;
    nblk    = (bid >> 3) & 7;
    s       = xcd * (S >> 3) + (bid >> 6);
  } else {
    nblk = bid % NB;
    s    = bid / NB;
  }
  int n0 = nblk * 128;
  int q = chunks / S, r = chunks % S;
  int myc = q + (s < r ? 1 : 0);
  int c0 = s*q + (s < r ? s : r);
  int k0 = c0 * 32;

  int wv = t >> 6, lane = t & 63;
  int wm = wv & 3, wn = wv >> 2;               // 4m x 2n
  int m0w = wm * 48;
  int n0w = wn * 64;
  int lrow = lane & 15, lg = lane >> 4;

  f32x4 acc[3][4];
#pragma unroll
  for (int i = 0; i < 3; ++i)
#pragma unroll
    for (int j = 0; j < 4; ++j) acc[i][j] = {0.f,0.f,0.f,0.f};

  u32x2 areg[3];
  float bv[8];
  const int am  = t >> 3;         // 0..63 (A row within 64-row pass)
  const int akp = (t & 7) * 2;    // u32-pair within 16-u32 row chunk
  const int bn  = t & 127;        // B: n within tile
  const int bk8 = (t >> 7) * 8;   // B: k-base (0,8,16,24)

  auto load_tile = [&](int it) {
    int kg = k0 + it*32;
#pragma unroll
    for (int i = 0; i < 3; ++i) {
      int m = am + i*64;
      areg[i] = *(const u32x2*)&A[(size_t)m*ldAu + (kg>>1) + akp];
    }
    int gn = n0 + bn;
    bool okn = (gn < N);
#pragma unroll
    for (int i = 0; i < 8; ++i) {
      int rr = kg + bk8 + i;
      size_t srow = PERM ? ((size_t)(rr & 255)*PP + (rr >> 8)) : (size_t)rr;
      bv[i] = okn ? Bm[srow*ldB + gn] : 0.f;
    }
  };

  load_tile(0);
  for (int it = 0; it < myc; ++it) {
    wg_barrier();      // readers of prev tile done; prefetch stays in flight
#pragma unroll
    for (int i = 0; i < 3; ++i) {
      int m = am + i*64;
      *(u32x2*)&lds_a[m*20 + akp] = areg[i];
    }
    {
      u32x2 w01 = { pk2(bv[0], bv[1]), pk2(bv[2], bv[3]) };
      u32x2 w23 = { pk2(bv[4], bv[5]), pk2(bv[6], bv[7]) };
      *(u32x2*)&lds_b[bn*18 + (bk8>>1)]     = w01;
      *(u32x2*)&lds_b[bn*18 + (bk8>>1) + 2] = w23;
    }
    wg_barrier();      // lgkmcnt(0) makes LDS writes visible; no vmcnt drain
    if (it + 1 < myc) load_tile(it + 1);      // overlap HBM with compute

    bf16x8 af[3];
#pragma unroll
    for (int mf = 0; mf < 3; ++mf) {
      u32x4 ra = *(const u32x4*)&lds_a[(m0w + mf*16 + lrow)*20 + lg*4];
      af[mf] = __builtin_bit_cast(bf16x8, ra);
    }
    bf16x8 bfrag[4];
#pragma unroll
    for (int nf = 0; nf < 4; ++nf) {
      int col = n0w + nf*16 + lrow;
      u32x2 r0 = *(const u32x2*)&lds_b[col*18 + lg*4];
      u32x2 r1 = *(const u32x2*)&lds_b[col*18 + lg*4 + 2];
      u32x4 ub = { r0[0], r0[1], r1[0], r1[1] };
      bfrag[nf] = __builtin_bit_cast(bf16x8, ub);
    }
#pragma unroll
    for (int nf = 0; nf < 4; ++nf)
#pragma unroll
      for (int mf = 0; mf < 3; ++mf)
        acc[mf][nf] = __builtin_amdgcn_mfma_f32_16x16x32_bf16(af[mf], bfrag[nf], acc[mf][nf], 0, 0, 0);
  }

#pragma unroll
  for (int mf = 0; mf < 3; ++mf) {
#pragma unroll
    for (int nf = 0; nf < 4; ++nf) {
      int gcol = n0 + n0w + nf*16 + lrow;
      if (gcol < N) {
#pragma unroll
        for (int rr = 0; rr < 4; ++rr) {
          int m = m0w + mf*16 + lg*4 + rr;
          partial[((size_t)s*NROIS + m)*N + gcol] = f2bf(acc[mf][nf][rr]);
        }
      }
    }
  }
}

// ------- reduce bf16 partials + bias + relu -> bf16 f (4 vals/thread) ---------
__global__ __launch_bounds__(256) void reduce_kernel(
    const unsigned short* __restrict__ partial, const float* __restrict__ bias,
    unsigned short* __restrict__ outp, int N, int S)
{
  int nn = (blockIdx.x*256 + threadIdx.x) * 4;
  int m  = blockIdx.y;
  if (nn >= N) return;
  f32x4 a = *(const f32x4*)&bias[nn];
  size_t stride = (size_t)NROIS * N;
  const unsigned short* p = &partial[(size_t)m*N + nn];
#pragma unroll 4
  for (int s = 0; s < S; ++s) {
    u32x2 v = *(const u32x2*)&p[(size_t)s*stride];
    a[0] += bf_lo(v[0]); a[1] += bf_hi(v[0]);
    a[2] += bf_lo(v[1]); a[3] += bf_hi(v[1]);
  }
  a[0] = fmaxf(a[0], 0.f); a[1] = fmaxf(a[1], 0.f);
  a[2] = fmaxf(a[2], 0.f); a[3] = fmaxf(a[3], 0.f);
  u32x2 pkd = { pk2(a[0], a[1]), pk2(a[2], a[3]) };
  *(u32x2*)&outp[(size_t)m*N + nn] = pkd;
}

// ------- reduce3: om[n][d] = b3[d] + sum_s p3[s][n][d]  (f32 out, 588 wide) ---
__global__ __launch_bounds__(640) void reduce3_kernel(
    const unsigned short* __restrict__ p3, const float* __restrict__ b3,
    float* __restrict__ om, int S)
{
  int d = threadIdx.x;
  int nn = blockIdx.x;
  if (d >= 3*PP) return;
  float a = b3[d];
#pragma unroll 4
  for (int s = 0; s < S; ++s)
    a += bf_u16(p3[((size_t)s*NROIS + nn)*(3*PP) + d]);
  om[(size_t)nn*(3*PP) + d] = a;
}

extern "C" void kernel_launch(void* const* d_in, const int* in_sizes, int n_in,
                              void* d_out, int out_size, void* d_ws, size_t ws_size,
                              hipStream_t stream)
{
  const float* x    = (const float*)d_in[0];
  const float* rois = (const float*)d_in[1];
  const float* w1   = (const float*)d_in[2];
  const float* b1   = (const float*)d_in[3];
  const float* w2   = (const float*)d_in[4];
  const float* b2   = (const float*)d_in[5];
  const float* w3   = (const float*)d_in[6];
  const float* b3   = (const float*)d_in[7];

  char* ws = (char*)d_ws;
  size_t off = 0;
  unsigned* xt = (unsigned*)(ws + off);               off += (size_t)2*(HH*WW)*(CCH/2)*4;
  unsigned short* base = (unsigned short*)(ws + off); off += (size_t)NROIS*KDIM*2;
  unsigned short* f1 = (unsigned short*)(ws + off);   off += (size_t)NROIS*FCDIM*2;
  unsigned short* f2 = (unsigned short*)(ws + off);   off += (size_t)NROIS*FCDIM*2;
  float* om = (float*)(ws + off);                     off += (size_t)NROIS*(3*PP)*4;
  const int S1 = 64, S2 = 32, S3 = 16;
  unsigned short* partial1 = (unsigned short*)(ws + off); off += (size_t)S1*NROIS*FCDIM*2;  // 25.2MB
  unsigned short* partial2 = (unsigned short*)(ws + off); off += (size_t)S2*NROIS*FCDIM*2;  // 12.6MB
  unsigned short* partial3 = (unsigned short*)(ws + off); off += (size_t)S3*NROIS*(3*PP)*2; // 3.6MB
  (void)ws_size;

  const int PBLK = (PP + 7) / 8;   // 25 bin-groups of 8

  // 1) transpose+bf16 x -> xt (v2: 128c x 64hw tiles)
  transpose_x_kernel<<<dim3((HH*WW)/64, CCH/128, 2), 256, 0, stream>>>(x, xt);
  // 2) base pool -> bf16 [192, 50176] (k = p*256+c)
  pool_kernel<0><<<dim3(NROIS, PBLK), 256, 0, stream>>>(xt, rois, nullptr, base);
  // 3) f1 = relu(base @ w1 + b1); 1568 K-chunks, 64 splits, XCD-swizzled
  gemm_splitk<1,1><<<8*S1, 512, 0, stream>>>((const unsigned*)base, KDIM/2, w1, FCDIM, FCDIM, partial1, 8, S1, KDIM/32);
  reduce_kernel<<<dim3(1, NROIS), 256, 0, stream>>>(partial1, b1, f1, FCDIM, S1);
  // 4) f2 = relu(f1 @ w2 + b2)
  gemm_splitk<0,1><<<8*S2, 512, 0, stream>>>((const unsigned*)f1, FCDIM/2, w2, FCDIM, FCDIM, partial2, 8, S2, FCDIM/32);
  reduce_kernel<<<dim3(1, NROIS), 256, 0, stream>>>(partial2, b2, f2, FCDIM, S2);
  // 5) partial3 = split-K of f2 @ w3 (N = 588)
  gemm_splitk<0,0><<<5*S3, 512, 0, stream>>>((const unsigned*)f2, FCDIM/2, w3, 3*PP, 3*PP, partial3, 5, S3, FCDIM/32);
  // 5b) om = b3 + sum partial3 (f32)
  reduce3_kernel<<<NROIS, 640, 0, stream>>>(partial3, b3, om, S3);
  // 6) final pool reads om, * sigmoid(mask) -> d_out
  pool_kernel<1><<<dim3(NROIS, PBLK), 256, 0, stream>>>(xt, rois, om, d_out);
}

// Round 15
// 143.421 us; speedup vs baseline: 1.2993x; 1.0008x over previous
//
#include <hip/hip_runtime.h>

#define PBIN 14
#define SSAMP 2
#define SCALE_F 0.0625f
#define TRANS_STD 0.1f
#define CCH 256
#define FCDIM 1024
#define NROIS 192
#define HH 128
#define WW 128
#define PP (PBIN*PBIN)      // 196
#define KDIM (CCH*PP)       // 50176

typedef __bf16 bf16x8 __attribute__((ext_vector_type(8)));
typedef float  f32x4  __attribute__((ext_vector_type(4)));
typedef unsigned u32x4 __attribute__((ext_vector_type(4)));
typedef unsigned u32x2 __attribute__((ext_vector_type(2)));

__device__ __forceinline__ unsigned short f2bf(float f) {
  unsigned u = __builtin_bit_cast(unsigned, f);
  u += 0x7FFFu + ((u >> 16) & 1u);   // RNE
  return (unsigned short)(u >> 16);
}
__device__ __forceinline__ unsigned pk2(float lo, float hi) {
  unsigned ulo = __builtin_bit_cast(unsigned, lo) + 0x8000u;
  unsigned uhi = __builtin_bit_cast(unsigned, hi) + 0x8000u;
  return __builtin_amdgcn_perm(uhi, ulo, 0x07060302u);
}
__device__ __forceinline__ float bf_lo(unsigned u) {
  return __builtin_bit_cast(float, u << 16);
}
__device__ __forceinline__ float bf_hi(unsigned u) {
  return __builtin_bit_cast(float, u & 0xFFFF0000u);
}
__device__ __forceinline__ float bf_u16(unsigned short v) {
  return __builtin_bit_cast(float, (unsigned)v << 16);
}

// Barrier without the vmcnt(0) drain __syncthreads() emits.
__device__ __forceinline__ void wg_barrier() {
  asm volatile("s_waitcnt lgkmcnt(0)" ::: "memory");
  __builtin_amdgcn_s_barrier();
  asm volatile("" ::: "memory");
}

// -------- transpose+convert x [B,C,H,W] f32 -> xt [B,H,W,C/2] u32(bf16 pair) --
// 128c x 64hw tile per block. Loads: f32x4/thread (256B wave segments).
// Stores: u32x4/thread (256B wave segments). LDS [128][65].
__global__ __launch_bounds__(256) void transpose_x_kernel(
    const float* __restrict__ x, unsigned* __restrict__ xt)
{
  __shared__ float tile[128][65];
  const int t   = threadIdx.x;
  const int hw0 = blockIdx.x * 64;
  const int c0  = blockIdx.y * 128;
  const int b   = blockIdx.z;
  const float* xb = x + (size_t)b * CCH * (HH*WW);
  unsigned* xtb   = xt + (size_t)b * (HH*WW) * (CCH/2);

#pragma unroll
  for (int i = 0; i < 8; ++i) {
    int v    = t + i*256;
    int crow = v >> 4;
    int hwc  = (v & 15) * 4;
    f32x4 d = *(const f32x4*)&xb[(size_t)(c0 + crow)*(HH*WW) + hw0 + hwc];
    tile[crow][hwc+0] = d[0];
    tile[crow][hwc+1] = d[1];
    tile[crow][hwc+2] = d[2];
    tile[crow][hwc+3] = d[3];
  }
  __syncthreads();
#pragma unroll
  for (int i = 0; i < 4; ++i) {
    int w   = t + i*256;
    int row = w >> 4;
    int q   = w & 15;
    u32x4 o = { pk2(tile[8*q+0][row], tile[8*q+1][row]),
                pk2(tile[8*q+2][row], tile[8*q+3][row]),
                pk2(tile[8*q+4][row], tile[8*q+5][row]),
                pk2(tile[8*q+6][row], tile[8*q+7][row]) };
    *(u32x4*)&xtb[(size_t)(hw0 + row)*(CCH/2) + (c0>>1) + 4*q] = o;
  }
}

// ---------------- PSRoI pool: HALF-WAVE = bin, lane = channel-oct -------------
// Block = 4 waves = 8 bins; factorized 2x2 taps (merged unique rows/cols).
// __launch_bounds__(256,8) pins VGPR<=64 (m69 occupancy cliff).
template<int MODE>
__global__ __launch_bounds__(256, 8) void pool_kernel(
    const unsigned* __restrict__ xt, const float* __restrict__ rois,
    const float* __restrict__ om, void* __restrict__ outp)
{
  __shared__ float lds[8][256];
  const int t = threadIdx.x;
  const int wv = t >> 6, lane = t & 63;
  const int h  = lane >> 5;
  const int j  = lane & 31;
  const int n  = blockIdx.x;
  const int p0 = blockIdx.y * 8;
  const int p  = p0 + wv*2 + h;
  const bool pok = (p < PP);
  const int pc = pok ? p : 0;
  const int ph = p / PBIN, pw = p % PBIN;

  float rb_ = rois[n*5 + 0];
  float x1 = rois[n*5 + 1], y1 = rois[n*5 + 2];
  float x2 = rois[n*5 + 3], y2 = rois[n*5 + 4];
  int b = (int)rb_;
  float sw = rintf(x1) * SCALE_F - 0.5f;
  float sh = rintf(y1) * SCALE_F - 0.5f;
  float ew = (rintf(x2) + 1.0f) * SCALE_F - 0.5f;
  float eh = (rintf(y2) + 1.0f) * SCALE_F - 0.5f;
  float rw = fmaxf(ew - sw, 0.1f);
  float rh = fmaxf(eh - sh, 0.1f);
  float bw = rw / PBIN, bh = rh / PBIN;
  float subw = bw / SSAMP, subh = bh / SSAMP;

  float tx = 0.f, ty = 0.f, mval = 1.f;
  if (MODE == 1) {
    const float* omr = om + (size_t)n * (3*PP);
    tx = omr[pc] * TRANS_STD;
    ty = omr[PP + pc] * TRANS_STD;
    mval = 1.0f / (1.0f + expf(-omr[2*PP + pc]));
  }
  float wstart = pw * bw + sw + tx * rw;
  float hstart = ph * bh + sh + ty * rh;

  // ---- X axis: two samples -> merged unique columns (nc in {2,3,4}) ----
  float wva = wstart, wvb = wstart + subw;
  float vxa = (wva >= -0.5f && wva <= WW - 0.5f) ? 1.f : 0.f;
  float vxb = (wvb >= -0.5f && wvb <= WW - 0.5f) ? 1.f : 0.f;
  float wca = fminf(fmaxf(wva, 0.f), WW - 1.0f);
  float wcb = fminf(fmaxf(wvb, 0.f), WW - 1.0f);
  int x0a = (int)floorf(wca), x0b = (int)floorf(wcb);
  int x1a = min(x0a + 1, WW - 1), x1b = min(x0b + 1, WW - 1);
  float lxa = wca - (float)x0a, lxb = wcb - (float)x0b;
  int cx0 = x0a, cx1 = x1a, cx2 = x0b, cx3 = x1b;
  float u0 = vxa*(1.f-lxa), u1 = vxa*lxa, u2 = vxb*(1.f-lxb), u3 = vxb*lxb;
  int nc;
  if (x0a == x0b)      { u0 += u2; u1 += u3; nc = 2; }
  else if (x1a == x0b) { u1 += u2; cx2 = x1b; u2 = u3; nc = 3; }
  else nc = 4;

  // ---- Y axis ----
  float hva = hstart, hvb = hstart + subh;
  float vya = (hva >= -0.5f && hva <= HH - 0.5f) ? 1.f : 0.f;
  float vyb = (hvb >= -0.5f && hvb <= HH - 0.5f) ? 1.f : 0.f;
  float hca = fminf(fmaxf(hva, 0.f), HH - 1.0f);
  float hcb = fminf(fmaxf(hvb, 0.f), HH - 1.0f);
  int y0a = (int)floorf(hca), y0b = (int)floorf(hcb);
  int y1a = min(y0a + 1, HH - 1), y1b = min(y0b + 1, HH - 1);
  float lya = hca - (float)y0a, lyb = hcb - (float)y0b;
  int ry0 = y0a, ry1 = y1a, ry2 = y0b, ry3 = y1b;
  float e0 = vya*(1.f-lya), e1 = vya*lya, e2 = vyb*(1.f-lyb), e3 = vyb*lyb;
  int nr;
  if (y0a == y0b)      { e0 += e2; e1 += e3; nr = 2; }
  else if (y1a == y0b) { e1 += e2; ry2 = y1b; e2 = e3; nr = 3; }
  else nr = 4;

  float cnt = (vxa + vxb) * (vya + vyb);
  float inv = 1.0f / fmaxf(cnt, 1.0f);
  if (MODE == 1) inv *= mval;

  const int base_b = b * (HH*WW);
  const int lofs = j * 4;
  f32x4 a01 = {0.f,0.f,0.f,0.f}, a23 = {0.f,0.f,0.f,0.f};

#define PCOL(CX, WX) {                                            \
    u32x4 v = *(const u32x4*)&xt[rbx + (CX)*(CCH/2)];             \
    float wq = wyr * (WX);                                        \
    a01[0] += wq * bf_lo(v[0]); a01[1] += wq * bf_hi(v[0]);       \
    a01[2] += wq * bf_lo(v[1]); a01[3] += wq * bf_hi(v[1]);       \
    a23[0] += wq * bf_lo(v[2]); a23[1] += wq * bf_hi(v[2]);       \
    a23[2] += wq * bf_lo(v[3]); a23[3] += wq * bf_hi(v[3]); }
#define PROW(RY, WY) {                                            \
    int rbx = (base_b + (RY)*WW)*(CCH/2) + lofs;                  \
    float wyr = (WY);                                             \
    PCOL(cx0, u0); PCOL(cx1, u1);                                 \
    if (nc > 2) PCOL(cx2, u2);                                    \
    if (nc > 3) PCOL(cx3, u3); }

  PROW(ry0, e0);
  PROW(ry1, e1);
  if (nr > 2) PROW(ry2, e2);
  if (nr > 3) PROW(ry3, e3);
#undef PROW
#undef PCOL

  a01 *= inv;
  a23 *= inv;

  if (MODE == 0) {
    if (pok) {
      unsigned short* bout = (unsigned short*)outp;
      u32x4 pkd = { pk2(a01[0], a01[1]), pk2(a01[2], a01[3]),
                    pk2(a23[0], a23[1]), pk2(a23[2], a23[3]) };
      *(u32x4*)&bout[(size_t)n*KDIM + p*CCH + j*8] = pkd;
    }
  } else {
    int bin = wv*2 + h;
    *(f32x4*)&lds[bin][j*8]     = a01;
    *(f32x4*)&lds[bin][j*8 + 4] = a23;
    __syncthreads();
    float* fout = (float*)outp;
    int c = t;
    f32x4 o0 = { lds[0][c], lds[1][c], lds[2][c], lds[3][c] };
    size_t ob = (size_t)n*KDIM + (size_t)c*PP + p0;
    *(f32x4*)&fout[ob] = o0;
    if (p0 + 8 <= PP) {
      f32x4 o1 = { lds[4][c], lds[5][c], lds[6][c], lds[7][c] };
      *(f32x4*)&fout[ob + 4] = o1;
    }
  }
}

// ---------------- split-K GEMM: partial[s] (bf16) = A(bf16 192xK) * bf16(B) ---
// BM=192, BN=128, BK=32, 8 waves as 4m x 2n. 1D grid NB*S.
// BALANCED K-partition: c0=(s*chunks)/S — the +1-chunk splits alternate in s,
// so each XCD (s = xcd*8+j under SWZ) gets an equal mix of heavy/light splits
// (old s<r rule put all heavy splits on XCDs 0-3: 4% tail on half the chip).
template<int PERM, int SWZ>
__global__ __launch_bounds__(512, 4) void gemm_splitk(
    const unsigned* __restrict__ A, int ldAu,
    const float* __restrict__ Bm, int N, int ldB,
    unsigned short* __restrict__ partial, int NB, int S, int chunks)
{
  __shared__ __align__(16) unsigned lds_a[192*20];   // [m][16 u32 + pad4]
  __shared__ __align__(16) unsigned lds_b[128*18];   // [n][16 u32(k-pairs) + pad2]

  int t   = threadIdx.x;
  int bid = blockIdx.x;
  int s, nblk;
  if (SWZ) {            // NB==8, S%8==0, grid%64==0
    int xcd = bid & 7;
    nblk    = (bid >> 3) & 7;
    s       = xcd * (S >> 3) + (bid >> 6);
  } else {
    nblk = bid % NB;
    s    = bid / NB;
  }
  int n0 = nblk * 128;
  int c0  = (s * chunks) / S;          // balanced partition
  int c1  = ((s + 1) * chunks) / S;
  int myc = c1 - c0;
  int k0 = c0 * 32;

  int wv = t >> 6, lane = t & 63;
  int wm = wv & 3, wn = wv >> 2;               // 4m x 2n
  int m0w = wm * 48;
  int n0w = wn * 64;
  int lrow = lane & 15, lg = lane >> 4;

  f32x4 acc[3][4];
#pragma unroll
  for (int i = 0; i < 3; ++i)
#pragma unroll
    for (int j = 0; j < 4; ++j) acc[i][j] = {0.f,0.f,0.f,0.f};

  u32x2 areg[3];
  float bv[8];
  const int am  = t >> 3;
  const int akp = (t & 7) * 2;
  const int bn  = t & 127;
  const int bk8 = (t >> 7) * 8;

  auto load_tile = [&](int it) {
    int kg = k0 + it*32;
#pragma unroll
    for (int i = 0; i < 3; ++i) {
      int m = am + i*64;
      areg[i] = *(const u32x2*)&A[(size_t)m*ldAu + (kg>>1) + akp];
    }
    int gn = n0 + bn;
    bool okn = (gn < N);
#pragma unroll
    for (int i = 0; i < 8; ++i) {
      int rr = kg + bk8 + i;
      size_t srow = PERM ? ((size_t)(rr & 255)*PP + (rr >> 8)) : (size_t)rr;
      bv[i] = okn ? Bm[srow*ldB + gn] : 0.f;
    }
  };

  load_tile(0);
  for (int it = 0; it < myc; ++it) {
    wg_barrier();      // readers of prev tile done; prefetch stays in flight
#pragma unroll
    for (int i = 0; i < 3; ++i) {
      int m = am + i*64;
      *(u32x2*)&lds_a[m*20 + akp] = areg[i];
    }
    {
      u32x2 w01 = { pk2(bv[0], bv[1]), pk2(bv[2], bv[3]) };
      u32x2 w23 = { pk2(bv[4], bv[5]), pk2(bv[6], bv[7]) };
      *(u32x2*)&lds_b[bn*18 + (bk8>>1)]     = w01;
      *(u32x2*)&lds_b[bn*18 + (bk8>>1) + 2] = w23;
    }
    wg_barrier();      // lgkmcnt(0) makes LDS writes visible; no vmcnt drain
    if (it + 1 < myc) load_tile(it + 1);      // overlap HBM with compute

    bf16x8 af[3];
#pragma unroll
    for (int mf = 0; mf < 3; ++mf) {
      u32x4 ra = *(const u32x4*)&lds_a[(m0w + mf*16 + lrow)*20 + lg*4];
      af[mf] = __builtin_bit_cast(bf16x8, ra);
    }
    bf16x8 bfrag[4];
#pragma unroll
    for (int nf = 0; nf < 4; ++nf) {
      int col = n0w + nf*16 + lrow;
      u32x2 r0 = *(const u32x2*)&lds_b[col*18 + lg*4];
      u32x2 r1 = *(const u32x2*)&lds_b[col*18 + lg*4 + 2];
      u32x4 ub = { r0[0], r0[1], r1[0], r1[1] };
      bfrag[nf] = __builtin_bit_cast(bf16x8, ub);
    }
#pragma unroll
    for (int nf = 0; nf < 4; ++nf)
#pragma unroll
      for (int mf = 0; mf < 3; ++mf)
        acc[mf][nf] = __builtin_amdgcn_mfma_f32_16x16x32_bf16(af[mf], bfrag[nf], acc[mf][nf], 0, 0, 0);
  }

#pragma unroll
  for (int mf = 0; mf < 3; ++mf) {
#pragma unroll
    for (int nf = 0; nf < 4; ++nf) {
      int gcol = n0 + n0w + nf*16 + lrow;
      if (gcol < N) {
#pragma unroll
        for (int rr = 0; rr < 4; ++rr) {
          int m = m0w + mf*16 + lg*4 + rr;
          partial[((size_t)s*NROIS + m)*N + gcol] = f2bf(acc[mf][nf][rr]);
        }
      }
    }
  }
}

// ------- reduce bf16 partials + bias + relu -> bf16 f (4 vals/thread) ---------
__global__ __launch_bounds__(256) void reduce_kernel(
    const unsigned short* __restrict__ partial, const float* __restrict__ bias,
    unsigned short* __restrict__ outp, int N, int S)
{
  int nn = (blockIdx.x*256 + threadIdx.x) * 4;
  int m  = blockIdx.y;
  if (nn >= N) return;
  f32x4 a = *(const f32x4*)&bias[nn];
  size_t stride = (size_t)NROIS * N;
  const unsigned short* p = &partial[(size_t)m*N + nn];
#pragma unroll 4
  for (int s = 0; s < S; ++s) {
    u32x2 v = *(const u32x2*)&p[(size_t)s*stride];
    a[0] += bf_lo(v[0]); a[1] += bf_hi(v[0]);
    a[2] += bf_lo(v[1]); a[3] += bf_hi(v[1]);
  }
  a[0] = fmaxf(a[0], 0.f); a[1] = fmaxf(a[1], 0.f);
  a[2] = fmaxf(a[2], 0.f); a[3] = fmaxf(a[3], 0.f);
  u32x2 pkd = { pk2(a[0], a[1]), pk2(a[2], a[3]) };
  *(u32x2*)&outp[(size_t)m*N + nn] = pkd;
}

// ------- reduce3: om[n][d] = b3[d] + sum_s p3[s][n][d]  (f32 out, 588 wide) ---
__global__ __launch_bounds__(640) void reduce3_kernel(
    const unsigned short* __restrict__ p3, const float* __restrict__ b3,
    float* __restrict__ om, int S)
{
  int d = threadIdx.x;
  int nn = blockIdx.x;
  if (d >= 3*PP) return;
  float a = b3[d];
#pragma unroll 4
  for (int s = 0; s < S; ++s)
    a += bf_u16(p3[((size_t)s*NROIS + nn)*(3*PP) + d]);
  om[(size_t)nn*(3*PP) + d] = a;
}

extern "C" void kernel_launch(void* const* d_in, const int* in_sizes, int n_in,
                              void* d_out, int out_size, void* d_ws, size_t ws_size,
                              hipStream_t stream)
{
  const float* x    = (const float*)d_in[0];
  const float* rois = (const float*)d_in[1];
  const float* w1   = (const float*)d_in[2];
  const float* b1   = (const float*)d_in[3];
  const float* w2   = (const float*)d_in[4];
  const float* b2   = (const float*)d_in[5];
  const float* w3   = (const float*)d_in[6];
  const float* b3   = (const float*)d_in[7];

  char* ws = (char*)d_ws;
  size_t off = 0;
  unsigned* xt = (unsigned*)(ws + off);               off += (size_t)2*(HH*WW)*(CCH/2)*4;
  unsigned short* base = (unsigned short*)(ws + off); off += (size_t)NROIS*KDIM*2;
  unsigned short* f1 = (unsigned short*)(ws + off);   off += (size_t)NROIS*FCDIM*2;
  unsigned short* f2 = (unsigned short*)(ws + off);   off += (size_t)NROIS*FCDIM*2;
  float* om = (float*)(ws + off);                     off += (size_t)NROIS*(3*PP)*4;
  const int S1 = 64, S2 = 32, S3 = 16;
  unsigned short* partial1 = (unsigned short*)(ws + off); off += (size_t)S1*NROIS*FCDIM*2;  // 25.2MB
  unsigned short* partial2 = (unsigned short*)(ws + off); off += (size_t)S2*NROIS*FCDIM*2;  // 12.6MB
  unsigned short* partial3 = (unsigned short*)(ws + off); off += (size_t)S3*NROIS*(3*PP)*2; // 3.6MB
  (void)ws_size;

  const int PBLK = (PP + 7) / 8;   // 25 bin-groups of 8

  // 1) transpose+bf16 x -> xt
  transpose_x_kernel<<<dim3((HH*WW)/64, CCH/128, 2), 256, 0, stream>>>(x, xt);
  // 2) base pool -> bf16 [192, 50176] (k = p*256+c)
  pool_kernel<0><<<dim3(NROIS, PBLK), 256, 0, stream>>>(xt, rois, nullptr, base);
  // 3) f1 = relu(base @ w1 + b1); 1568 K-chunks, 64 splits, XCD-swizzled,
  //    balanced partition (heavy splits interleaved across XCDs)
  gemm_splitk<1,1><<<8*S1, 512, 0, stream>>>((const unsigned*)base, KDIM/2, w1, FCDIM, FCDIM, partial1, 8, S1, KDIM/32);
  reduce_kernel<<<dim3(1, NROIS), 256, 0, stream>>>(partial1, b1, f1, FCDIM, S1);
  // 4) f2 = relu(f1 @ w2 + b2)
  gemm_splitk<0,1><<<8*S2, 512, 0, stream>>>((const unsigned*)f1, FCDIM/2, w2, FCDIM, FCDIM, partial2, 8, S2, FCDIM/32);
  reduce_kernel<<<dim3(1, NROIS), 256, 0, stream>>>(partial2, b2, f2, FCDIM, S2);
  // 5) partial3 = split-K of f2 @ w3 (N = 588)
  gemm_splitk<0,0><<<5*S3, 512, 0, stream>>>((const unsigned*)f2, FCDIM/2, w3, 3*PP, 3*PP, partial3, 5, S3, FCDIM/32);
  // 5b) om = b3 + sum partial3 (f32)
  reduce3_kernel<<<NROIS, 640, 0, stream>>>(partial3, b3, om, S3);
  // 6) final pool reads om, * sigmoid(mask) -> d_out
  pool_kernel<1><<<dim3(NROIS, PBLK), 256, 0, stream>>>(xt, rois, om, d_out);
}